// Round 4
// baseline (1487.568 us; speedup 1.0000x reference)
//
#include <hip/hip_runtime.h>

using short8  = __attribute__((ext_vector_type(8))) short;
using ushort8 = __attribute__((ext_vector_type(8))) unsigned short;
using f32x4   = __attribute__((ext_vector_type(4))) float;
using fvec4   = __attribute__((ext_vector_type(4))) float;

#define CH 8192        // edges per hist/scatter block
#define XSTE 80        // x LDS row stride in shorts (160B, 16B-aligned)
#define PDST 72        // pd LDS row stride in shorts (144B, 16B-aligned)
#define ASTE 65        // agg LDS row stride in floats (odd => banks spread by row)

__device__ inline unsigned short f2bf(float x) {
  unsigned int u = __float_as_uint(x);
  unsigned int r = (u + 0x7FFFu + ((u >> 16) & 1u)) >> 16;
  return (unsigned short)r;
}
__device__ inline float bf2f(unsigned short s) {
  return __uint_as_float(((unsigned int)s) << 16);
}
__device__ inline short8 cvt8(fvec4 a, fvec4 b) {
  short8 r;
#pragma unroll
  for (int i = 0; i < 4; ++i) { r[i] = (short)f2bf(a[i]); r[i + 4] = (short)f2bf(b[i]); }
  return r;
}

// B fragments for [64x64] W (row-major f32): lane holds B[k=ks*32+lh*8+i][col=ct*16+l15]
__device__ inline void load_bfrags(const float* __restrict__ W, short8 bfr[2][4], int lane) {
  int l15 = lane & 15, lh = lane >> 4;
#pragma unroll
  for (int ks = 0; ks < 2; ++ks)
#pragma unroll
    for (int ct = 0; ct < 4; ++ct) {
      short8 v;
#pragma unroll
      for (int i = 0; i < 8; ++i)
        v[i] = (short)f2bf(W[(ks * 32 + lh * 8 + i) * 64 + ct * 16 + l15]);
      bfr[ks][ct] = v;
    }
}

struct ProjArgs {
  const float* W[6];
  unsigned short* out[6];
};

// all 6 projections of h in one pass (read h once)
__global__ __launch_bounds__(256) void proj_all_kernel(const float* __restrict__ h, ProjArgs pa, int N) {
  int lane = threadIdx.x & 63;
  int wv = threadIdx.x >> 6;
  int rowbase = blockIdx.x * 256 + wv * 64;
  int l15 = lane & 15, lh = lane >> 4;

  short8 afr[4][2];
#pragma unroll
  for (int rt = 0; rt < 4; ++rt) {
    int row = rowbase + rt * 16 + l15;
    int rc = row < N ? row : 0;
    const fvec4* p = reinterpret_cast<const fvec4*>(h + (size_t)rc * 64);
#pragma unroll
    for (int ks = 0; ks < 2; ++ks)
      afr[rt][ks] = cvt8(p[ks * 8 + lh * 2], p[ks * 8 + lh * 2 + 1]);
  }

  for (int z = 0; z < 6; ++z) {
    short8 bfr[2][4];
    load_bfrags(pa.W[z], bfr, lane);
    unsigned short* __restrict__ out = pa.out[z];

    f32x4 acc[4][4];
#pragma unroll
    for (int rt = 0; rt < 4; ++rt)
#pragma unroll
      for (int ct = 0; ct < 4; ++ct) acc[rt][ct] = (f32x4){0.f, 0.f, 0.f, 0.f};

#pragma unroll
    for (int rt = 0; rt < 4; ++rt)
#pragma unroll
      for (int ks = 0; ks < 2; ++ks)
#pragma unroll
        for (int ct = 0; ct < 4; ++ct)
          acc[rt][ct] = __builtin_amdgcn_mfma_f32_16x16x32_bf16(afr[rt][ks], bfr[ks][ct], acc[rt][ct], 0, 0, 0);

#pragma unroll
    for (int rt = 0; rt < 4; ++rt)
#pragma unroll
      for (int rg = 0; rg < 4; ++rg) {
        int row = rowbase + rt * 16 + lh * 4 + rg;
        if (row < N) {
#pragma unroll
          for (int ct = 0; ct < 4; ++ct)
            out[(size_t)row * 64 + ct * 16 + l15] = f2bf(acc[rt][ct][rg]);
        }
      }
  }
}

// ---- bucket histogram (bin = dst>>6), LDS-aggregated ----
__global__ __launch_bounds__(256) void hist_kernel(const int* __restrict__ dst0, const int* __restrict__ dst1,
                                                   int* __restrict__ counts, int E, int NBK) {
  __shared__ int hcnt[2048];
  int z = blockIdx.y;
  const int* __restrict__ dst = z ? dst1 : dst0;
  int t = threadIdx.x;
  for (int i = t; i < NBK; i += 256) hcnt[i] = 0;
  __syncthreads();
  int base = blockIdx.x * CH;
#pragma unroll 4
  for (int k = 0; k < CH / 256; ++k) {
    int i = base + k * 256 + t;
    if (i < E) atomicAdd(&hcnt[dst[i] >> 6], 1);
  }
  __syncthreads();
  for (int i = t; i < NBK; i += 256) {
    int c = hcnt[i];
    if (c) atomicAdd(&counts[(size_t)z * NBK + i], c);
  }
}

// exclusive scan of counts -> cursor (preserved) and gcur (working copy)
__global__ __launch_bounds__(1024) void scan_kernel(const int* __restrict__ counts, int* __restrict__ cursor,
                                                    int* __restrict__ gcur, int NBK) {
  int z = blockIdx.x;
  const int* c = counts + (size_t)z * NBK;
  __shared__ int lds[1024];
  int t = threadIdx.x;
  int carry = 0;
  for (int base = 0; base < NBK; base += 1024) {
    int i = base + t;
    int v = (i < NBK) ? c[i] : 0;
    lds[t] = v;
    __syncthreads();
    for (int off = 1; off < 1024; off <<= 1) {
      int x = (t >= off) ? lds[t - off] : 0;
      __syncthreads();
      lds[t] += x;
      __syncthreads();
    }
    if (i < NBK) {
      int excl = carry + lds[t] - v;
      cursor[(size_t)z * NBK + i] = excl;
      gcur[(size_t)z * NBK + i] = excl;
    }
    carry += lds[1023];
    __syncthreads();
  }
}

// ---- bucket scatter with per-block rank aggregation ----
// record: x = el | (dlocal<<21), y = src   (E < 2^21, dlocal < 64)
__global__ __launch_bounds__(256) void scatter_kernel(
    const int* __restrict__ src0, const int* __restrict__ dst0,
    const int* __restrict__ src1, const int* __restrict__ dst1,
    int* __restrict__ gcur, int2* __restrict__ recs0, int2* __restrict__ recs1,
    int E, int NBK) {
  __shared__ int lcnt[2048];
  int z = blockIdx.y;
  const int* __restrict__ src = z ? src1 : src0;
  const int* __restrict__ dst = z ? dst1 : dst0;
  int2* __restrict__ recs = z ? recs1 : recs0;
  int t = threadIdx.x;
  for (int i = t; i < NBK; i += 256) lcnt[i] = 0;
  __syncthreads();
  int base = blockIdx.x * CH;
#pragma unroll 4
  for (int k = 0; k < CH / 256; ++k) {
    int i = base + k * 256 + t;
    if (i < E) atomicAdd(&lcnt[dst[i] >> 6], 1);
  }
  __syncthreads();
  for (int i = t; i < NBK; i += 256) {
    int c = lcnt[i];
    lcnt[i] = c ? atomicAdd(&gcur[(size_t)z * NBK + i], c) : 0;
  }
  __syncthreads();
#pragma unroll 4
  for (int k = 0; k < CH / 256; ++k) {
    int i = base + k * 256 + t;
    if (i < E) {
      int d = dst[i], s = src[i];
      int bin = d >> 6, dl = d & 63;
      int pos = atomicAdd(&lcnt[bin], 1);
      recs[pos] = make_int2(i | (dl << 21), s);
    }
  }
}

// ---- edge GEMM per dst-bucket; LDS f32 atomic aggregation; coalesced agg store ----
__global__ __launch_bounds__(256) void edge_bucket_kernel(
    const float* __restrict__ e, const int2* __restrict__ recs,
    const float* __restrict__ W, const float* __restrict__ bmsg,
    const unsigned short* __restrict__ Psrc, const unsigned short* __restrict__ Pdst,
    float* __restrict__ agg, const int* __restrict__ bstart, const int* __restrict__ bcnt,
    int N, int E) {
  __shared__ float agg_lds[64 * ASTE];            // 16.6 KB
  __shared__ unsigned short pd_lds[64 * PDST];    // 9.2 KB
  __shared__ unsigned short x_lds[4][64 * XSTE];  // 40.9 KB
  int b = blockIdx.x;
  int t = threadIdx.x;
  int lane = t & 63, wv = t >> 6;
  int l15 = lane & 15, lh = lane >> 4;
  int chunk = lane & 7, row8 = lane >> 3;
  int node0 = b << 6;
  int start = bstart[b], cnt = bcnt[b];

  // init: zero agg tile, preload Pdst rows for this bucket (coalesced)
  for (int i = t; i < 64 * ASTE; i += 256) agg_lds[i] = 0.f;
  {
    int r = t >> 2, cb = (t & 3) * 16;
    int node = node0 + r;
    ushort8 v0 = {0, 0, 0, 0, 0, 0, 0, 0}, v1 = v0;
    if (node < N) {
      const ushort8* p = reinterpret_cast<const ushort8*>(Pdst + ((size_t)node << 6) + cb);
      v0 = p[0];
      v1 = p[1];
    }
    *reinterpret_cast<ushort8*>(pd_lds + r * PDST + cb) = v0;
    *reinterpret_cast<ushort8*>(pd_lds + r * PDST + cb + 8) = v1;
  }

  short8 bfr[2][4];
  load_bfrags(W, bfr, lane);
  float bv8[8];
  {
    const fvec4* bp = reinterpret_cast<const fvec4*>(bmsg + chunk * 8);
    fvec4 b0 = bp[0], b1 = bp[1];
#pragma unroll
    for (int j = 0; j < 4; ++j) { bv8[j] = b0[j]; bv8[j + 4] = b1[j]; }
  }
  __syncthreads();

  unsigned short* xw = &x_lds[wv][0];
  int ntiles = (cnt + 63) >> 6;

  for (int tile = wv; tile < ntiles; tile += 4) {
    int off = tile * 64 + lane;
    int el = 0, dl = -1, s = 0;
    if (off < cnt) {
      int2 rc = recs[start + off];
      el = rc.x & 0x1FFFFF;
      dl = (rc.x >> 21) & 63;
      s = rc.y;
    }

    // Psrc gather straight into regs: lane covers rows i*8+row8, cols chunk*8..+7
    ushort8 psv[8];
#pragma unroll
    for (int i = 0; i < 8; ++i) {
      int sr = __shfl(s, i * 8 + row8);
      psv[i] = *reinterpret_cast<const ushort8*>(Psrc + ((size_t)sr << 6) + chunk * 8);
    }

    // e-row GEMM
    f32x4 acc[4][4];
#pragma unroll
    for (int rt = 0; rt < 4; ++rt)
#pragma unroll
      for (int ct = 0; ct < 4; ++ct) acc[rt][ct] = (f32x4){0.f, 0.f, 0.f, 0.f};
#pragma unroll
    for (int rt = 0; rt < 4; ++rt) {
      int er = __shfl(el, rt * 16 + l15);
      const fvec4* pr = reinterpret_cast<const fvec4*>(e + ((size_t)er << 6));
#pragma unroll
      for (int ks = 0; ks < 2; ++ks) {
        short8 a = cvt8(pr[ks * 8 + lh * 2], pr[ks * 8 + lh * 2 + 1]);
#pragma unroll
        for (int ct = 0; ct < 4; ++ct)
          acc[rt][ct] = __builtin_amdgcn_mfma_f32_16x16x32_bf16(a, bfr[ks][ct], acc[rt][ct], 0, 0, 0);
      }
    }

    // stash x = bf16(acc) into swizzled LDS tile (per-wave private)
#pragma unroll
    for (int rt = 0; rt < 4; ++rt)
#pragma unroll
      for (int rg = 0; rg < 4; ++rg) {
        int row = rt * 16 + lh * 4 + rg;
        int q = (row & 7) << 3;
#pragma unroll
        for (int ct = 0; ct < 4; ++ct)
          xw[row * XSTE + ((ct * 16 + l15) ^ q)] = f2bf(acc[rt][ct][rg]);
      }
    asm volatile("s_waitcnt lgkmcnt(0)" ::: "memory");
    __builtin_amdgcn_sched_barrier(0);

    // flush: lane handles rows i*8+row8, cols chunk*8..+7
#pragma unroll
    for (int i = 0; i < 8; ++i) {
      int r = i * 8 + row8;
      int dlr = __shfl(dl, r);
      if (dlr < 0) continue;
      short8 xv = *reinterpret_cast<short8*>(xw + r * XSTE + ((chunk ^ (r & 7)) * 8));
      short8 pdv = *reinterpret_cast<short8*>(pd_lds + dlr * PDST + chunk * 8);
#pragma unroll
      for (int j = 0; j < 8; ++j) {
        float v = bf2f((unsigned short)xv[j]) + bf2f(psv[i][j]) + bf2f((unsigned short)pdv[j]) + bv8[j];
        atomicAdd(&agg_lds[dlr * ASTE + chunk * 8 + j], fmaxf(v, 0.f));
      }
    }
  }
  __syncthreads();

  // exclusive coalesced store of the bucket's agg tile
  {
    int r = t >> 2, cb = (t & 3) * 16;
    int node = node0 + r;
    if (node < N) {
#pragma unroll
      for (int j = 0; j < 16; ++j)
        agg[((size_t)node << 6) + cb + j] = agg_lds[r * ASTE + cb + j];
    }
  }
}

struct NodeArgs {
  const float* agg[2];
  const unsigned short* T[2];
  const float* W[2];
  const float* bn[2];
  unsigned short* U[2];
};

// U = bf16(relu(T + agg@Wagg + b_node)); agg split hi+lo bf16 for accuracy
__global__ __launch_bounds__(256) void node_kernel(NodeArgs na, int N) {
  int z = blockIdx.y;
  const float* __restrict__ agg = na.agg[z];
  const unsigned short* __restrict__ T = na.T[z];
  const float* __restrict__ bn = na.bn[z];
  unsigned short* __restrict__ U = na.U[z];
  int lane = threadIdx.x & 63;
  int wv = threadIdx.x >> 6;
  int rowbase = blockIdx.x * 256 + wv * 64;
  int l15 = lane & 15, lh = lane >> 4;

  short8 bfr[2][4];
  load_bfrags(na.W[z], bfr, lane);

  f32x4 acc[4][4];
#pragma unroll
  for (int rt = 0; rt < 4; ++rt)
#pragma unroll
    for (int ct = 0; ct < 4; ++ct) acc[rt][ct] = (f32x4){0.f, 0.f, 0.f, 0.f};

#pragma unroll
  for (int rt = 0; rt < 4; ++rt) {
    int row = rowbase + rt * 16 + l15;
    int rc = row < N ? row : 0;
    const fvec4* p = reinterpret_cast<const fvec4*>(agg + (size_t)rc * 64);
#pragma unroll
    for (int ks = 0; ks < 2; ++ks) {
      fvec4 p0 = p[ks * 8 + lh * 2], p1 = p[ks * 8 + lh * 2 + 1];
      short8 ahi = cvt8(p0, p1);
      fvec4 q0, q1;
#pragma unroll
      for (int i = 0; i < 4; ++i) {
        q0[i] = p0[i] - bf2f((unsigned short)ahi[i]);
        q1[i] = p1[i] - bf2f((unsigned short)ahi[i + 4]);
      }
      short8 alo = cvt8(q0, q1);
#pragma unroll
      for (int ct = 0; ct < 4; ++ct) {
        acc[rt][ct] = __builtin_amdgcn_mfma_f32_16x16x32_bf16(ahi, bfr[ks][ct], acc[rt][ct], 0, 0, 0);
        acc[rt][ct] = __builtin_amdgcn_mfma_f32_16x16x32_bf16(alo, bfr[ks][ct], acc[rt][ct], 0, 0, 0);
      }
    }
  }

  float bv[4];
#pragma unroll
  for (int ct = 0; ct < 4; ++ct) bv[ct] = bn[ct * 16 + l15];

#pragma unroll
  for (int rt = 0; rt < 4; ++rt)
#pragma unroll
    for (int rg = 0; rg < 4; ++rg) {
      int row = rowbase + rt * 16 + lh * 4 + rg;
      if (row < N) {
#pragma unroll
        for (int ct = 0; ct < 4; ++ct) {
          int c = ct * 16 + l15;
          float v = acc[rt][ct][rg] + bf2f(T[(size_t)row * 64 + c]) + bv[ct];
          U[(size_t)row * 64 + c] = f2bf(fmaxf(v, 0.0f));
        }
      }
    }
}

// attention over the 2-way stack; 4 threads per node
__global__ __launch_bounds__(256) void attn_kernel(
    const unsigned short* __restrict__ U0, const unsigned short* __restrict__ U1,
    const float* __restrict__ l1w, const float* __restrict__ l1b, const float* __restrict__ l2w,
    float* __restrict__ out, int N) {
  int t = threadIdx.x;
  int node = blockIdx.x * 64 + (t >> 2);
  int q = t & 3;
  if (node >= N) return;
  size_t b0 = (size_t)node * 64;

  float a0[8], a1[8];
#pragma unroll
  for (int i = 0; i < 8; ++i) { a0[i] = l1b[q * 8 + i]; a1[i] = a0[i]; }

  for (int k = 0; k < 64; ++k) {
    float u0 = bf2f(U0[b0 + k]);
    float u1 = bf2f(U1[b0 + k]);
#pragma unroll
    for (int i = 0; i < 8; ++i) {
      float w = l1w[k * 32 + q * 8 + i];
      a0[i] += u0 * w;
      a1[i] += u1 * w;
    }
  }
  float w0 = 0.f, w1 = 0.f;
#pragma unroll
  for (int i = 0; i < 8; ++i) {
    float l2 = l2w[q * 8 + i];
    w0 += tanhf(a0[i]) * l2;
    w1 += tanhf(a1[i]) * l2;
  }
  w0 += __shfl_xor(w0, 1, 4); w0 += __shfl_xor(w0, 2, 4);
  w1 += __shfl_xor(w1, 1, 4); w1 += __shfl_xor(w1, 2, 4);

  float m = fmaxf(w0, w1);
  float e0 = expf(w0 - m), e1 = expf(w1 - m);
  float inv = 1.0f / (e0 + e1);
  float be0 = e0 * inv, be1 = e1 * inv;

#pragma unroll
  for (int j = 0; j < 16; ++j) {
    int c = q * 16 + j;
    out[b0 + c] = be0 * bf2f(U0[b0 + c]) + be1 * bf2f(U1[b0 + c]);
  }
}

static inline size_t au(size_t x) { return (x + 255) & ~(size_t)255; }

extern "C" void kernel_launch(void* const* d_in, const int* in_sizes, int n_in,
                              void* d_out, int out_size, void* d_ws, size_t ws_size,
                              hipStream_t stream) {
  const float* h      = (const float*)d_in[0];
  const float* e_od   = (const float*)d_in[1];
  const float* e_ad   = (const float*)d_in[2];
  const int* src_od   = (const int*)d_in[3];
  const int* dst_od   = (const int*)d_in[4];
  const int* src_ad   = (const int*)d_in[5];
  const int* dst_ad   = (const int*)d_in[6];
  const float* W_src  = (const float*)d_in[7];
  const float* W_dst  = (const float*)d_in[8];
  const float* W_edge = (const float*)d_in[9];
  const float* b_msg  = (const float*)d_in[10];
  const float* W_self = (const float*)d_in[11];
  const float* W_agg  = (const float*)d_in[12];
  const float* b_node = (const float*)d_in[13];
  const float* l1w    = (const float*)d_in[14];
  const float* l1b    = (const float*)d_in[15];
  const float* l2w    = (const float*)d_in[16];
  float* out = (float*)d_out;

  int N = in_sizes[0] / 64;
  int E = in_sizes[1] / 64;
  int NBK = (N + 63) >> 6;  // 64-node dst buckets

  char* ws = (char*)d_ws;
  size_t off = 0;
  int* counts = (int*)(ws + off);   off += au((size_t)2 * NBK * sizeof(int));
  size_t zero_bytes = off;          // only counts needs zeroing
  int* cursor = (int*)(ws + off);   off += au((size_t)2 * NBK * sizeof(int));
  int* gcur   = (int*)(ws + off);   off += au((size_t)2 * NBK * sizeof(int));
  int2* recs0 = (int2*)(ws + off);  off += au((size_t)E * sizeof(int2));
  int2* recs1 = (int2*)(ws + off);  off += au((size_t)E * sizeof(int2));
  float* agg0 = (float*)(ws + off); off += (size_t)N * 64 * sizeof(float);
  float* agg1 = (float*)(ws + off); off += (size_t)N * 64 * sizeof(float);
  size_t NP = au((size_t)N * 64 * sizeof(unsigned short));
  unsigned short* Psrc0 = (unsigned short*)(ws + off); off += NP;
  unsigned short* Pdst0 = (unsigned short*)(ws + off); off += NP;
  unsigned short* Psrc1 = (unsigned short*)(ws + off); off += NP;
  unsigned short* Pdst1 = (unsigned short*)(ws + off); off += NP;
  unsigned short* T0    = (unsigned short*)(ws + off); off += NP;
  unsigned short* T1    = (unsigned short*)(ws + off); off += NP;
  unsigned short* U0 = Psrc0;  // dead after edge pass of graph 0
  unsigned short* U1 = Psrc1;  // dead after edge pass of graph 1

  hipMemsetAsync(ws, 0, zero_bytes, stream);

  int nb = (N + 255) / 256;
  ProjArgs pa;
  pa.W[0] = W_src;         pa.out[0] = Psrc0;
  pa.W[1] = W_dst;         pa.out[1] = Pdst0;
  pa.W[2] = W_src + 4096;  pa.out[2] = Psrc1;
  pa.W[3] = W_dst + 4096;  pa.out[3] = Pdst1;
  pa.W[4] = W_self;        pa.out[4] = T0;
  pa.W[5] = W_self + 4096; pa.out[5] = T1;
  proj_all_kernel<<<nb, 256, 0, stream>>>(h, pa, N);

  int nch = (E + CH - 1) / CH;
  hist_kernel<<<dim3(nch, 2), 256, 0, stream>>>(dst_od, dst_ad, counts, E, NBK);
  scan_kernel<<<2, 1024, 0, stream>>>(counts, cursor, gcur, NBK);
  scatter_kernel<<<dim3(nch, 2), 256, 0, stream>>>(src_od, dst_od, src_ad, dst_ad, gcur,
                                                   recs0, recs1, E, NBK);

  edge_bucket_kernel<<<NBK, 256, 0, stream>>>(e_od, recs0, W_edge, b_msg,
                                              Psrc0, Pdst0, agg0, cursor, counts, N, E);
  edge_bucket_kernel<<<NBK, 256, 0, stream>>>(e_ad, recs1, W_edge + 4096, b_msg + 64,
                                              Psrc1, Pdst1, agg1, cursor + NBK, counts + NBK, N, E);

  NodeArgs na;
  na.agg[0] = agg0; na.T[0] = T0; na.W[0] = W_agg;        na.bn[0] = b_node;      na.U[0] = U0;
  na.agg[1] = agg1; na.T[1] = T1; na.W[1] = W_agg + 4096; na.bn[1] = b_node + 64; na.U[1] = U1;
  node_kernel<<<dim3(nb, 2), 256, 0, stream>>>(na, N);

  attn_kernel<<<(N + 63) / 64, 256, 0, stream>>>(U0, U1, l1w, l1b, l2w, out, N);
}

// Round 5
// 670.004 us; speedup vs baseline: 2.2202x; 2.2202x over previous
//
#include <hip/hip_runtime.h>

using short8  = __attribute__((ext_vector_type(8))) short;
using ushort8 = __attribute__((ext_vector_type(8))) unsigned short;
using f32x4   = __attribute__((ext_vector_type(4))) float;
using fvec4   = __attribute__((ext_vector_type(4))) float;

#define CH 8192   // edges per hist/scatter block
#define XST 72    // x LDS row stride in shorts (144B, 16B-aligned)

__device__ inline unsigned short f2bf(float x) {
  unsigned int u = __float_as_uint(x);
  unsigned int r = (u + 0x7FFFu + ((u >> 16) & 1u)) >> 16;
  return (unsigned short)r;
}
__device__ inline float bf2f(unsigned short s) {
  return __uint_as_float(((unsigned int)s) << 16);
}
__device__ inline short8 cvt8(fvec4 a, fvec4 b) {
  short8 r;
#pragma unroll
  for (int i = 0; i < 4; ++i) { r[i] = (short)f2bf(a[i]); r[i + 4] = (short)f2bf(b[i]); }
  return r;
}

// B fragments for [64x64] W (row-major f32): lane holds B[k=ks*32+lh*8+i][col=ct*16+l15]
__device__ inline void load_bfrags(const float* __restrict__ W, short8 bfr[2][4], int lane) {
  int l15 = lane & 15, lh = lane >> 4;
#pragma unroll
  for (int ks = 0; ks < 2; ++ks)
#pragma unroll
    for (int ct = 0; ct < 4; ++ct) {
      short8 v;
#pragma unroll
      for (int i = 0; i < 8; ++i)
        v[i] = (short)f2bf(W[(ks * 32 + lh * 8 + i) * 64 + ct * 16 + l15]);
      bfr[ks][ct] = v;
    }
}

struct ProjArgs {
  const float* W[6];
  unsigned short* out[6];
};

// all 6 projections of h in one pass (read h once)
__global__ __launch_bounds__(256) void proj_all_kernel(const float* __restrict__ h, ProjArgs pa, int N) {
  int lane = threadIdx.x & 63;
  int wv = threadIdx.x >> 6;
  int rowbase = blockIdx.x * 256 + wv * 64;
  int l15 = lane & 15, lh = lane >> 4;

  short8 afr[4][2];
#pragma unroll
  for (int rt = 0; rt < 4; ++rt) {
    int row = rowbase + rt * 16 + l15;
    int rc = row < N ? row : 0;
    const fvec4* p = reinterpret_cast<const fvec4*>(h + (size_t)rc * 64);
#pragma unroll
    for (int ks = 0; ks < 2; ++ks)
      afr[rt][ks] = cvt8(p[ks * 8 + lh * 2], p[ks * 8 + lh * 2 + 1]);
  }

  for (int z = 0; z < 6; ++z) {
    short8 bfr[2][4];
    load_bfrags(pa.W[z], bfr, lane);
    unsigned short* __restrict__ out = pa.out[z];

    f32x4 acc[4][4];
#pragma unroll
    for (int rt = 0; rt < 4; ++rt)
#pragma unroll
      for (int ct = 0; ct < 4; ++ct) acc[rt][ct] = (f32x4){0.f, 0.f, 0.f, 0.f};

#pragma unroll
    for (int rt = 0; rt < 4; ++rt)
#pragma unroll
      for (int ks = 0; ks < 2; ++ks)
#pragma unroll
        for (int ct = 0; ct < 4; ++ct)
          acc[rt][ct] = __builtin_amdgcn_mfma_f32_16x16x32_bf16(afr[rt][ks], bfr[ks][ct], acc[rt][ct], 0, 0, 0);

#pragma unroll
    for (int rt = 0; rt < 4; ++rt)
#pragma unroll
      for (int rg = 0; rg < 4; ++rg) {
        int row = rowbase + rt * 16 + lh * 4 + rg;
        if (row < N) {
#pragma unroll
          for (int ct = 0; ct < 4; ++ct)
            out[(size_t)row * 64 + ct * 16 + l15] = f2bf(acc[rt][ct][rg]);
        }
      }
  }
}

// ---- bucket histogram (bin = dst>>6), LDS-aggregated ----
__global__ __launch_bounds__(256) void hist_kernel(const int* __restrict__ dst0, const int* __restrict__ dst1,
                                                   int* __restrict__ counts, int E, int NBK) {
  __shared__ int hcnt[2048];
  int z = blockIdx.y;
  const int* __restrict__ dst = z ? dst1 : dst0;
  int t = threadIdx.x;
  for (int i = t; i < NBK; i += 256) hcnt[i] = 0;
  __syncthreads();
  int base = blockIdx.x * CH;
#pragma unroll 4
  for (int k = 0; k < CH / 256; ++k) {
    int i = base + k * 256 + t;
    if (i < E) atomicAdd(&hcnt[dst[i] >> 6], 1);
  }
  __syncthreads();
  for (int i = t; i < NBK; i += 256) {
    int c = hcnt[i];
    if (c) atomicAdd(&counts[(size_t)z * NBK + i], c);
  }
}

// exclusive scan of bucket counts -> cursor (preserved) and gcur (working copy)
__global__ __launch_bounds__(1024) void scan_kernel(const int* __restrict__ counts, int* __restrict__ cursor,
                                                    int* __restrict__ gcur, int NBK) {
  int z = blockIdx.x;
  const int* c = counts + (size_t)z * NBK;
  __shared__ int lds[1024];
  int t = threadIdx.x;
  int carry = 0;
  for (int base = 0; base < NBK; base += 1024) {
    int i = base + t;
    int v = (i < NBK) ? c[i] : 0;
    lds[t] = v;
    __syncthreads();
    for (int off = 1; off < 1024; off <<= 1) {
      int x = (t >= off) ? lds[t - off] : 0;
      __syncthreads();
      lds[t] += x;
      __syncthreads();
    }
    if (i < NBK) {
      int excl = carry + lds[t] - v;
      cursor[(size_t)z * NBK + i] = excl;
      gcur[(size_t)z * NBK + i] = excl;
    }
    carry += lds[1023];
    __syncthreads();
  }
}

// ---- phase A: bucket scatter with per-block rank aggregation ----
// packed record: x = el | (bin<<21)   (el<2^21, bin<2^11)
//                y = src | (dl<<26)   (src<2^26, dl<64)
__global__ __launch_bounds__(256) void scatterA_kernel(
    const int* __restrict__ src0, const int* __restrict__ dst0,
    const int* __restrict__ src1, const int* __restrict__ dst1,
    int* __restrict__ gcur, int2* __restrict__ recs0, int2* __restrict__ recs1,
    int E, int NBK) {
  __shared__ int lcnt[2048];
  int z = blockIdx.y;
  const int* __restrict__ src = z ? src1 : src0;
  const int* __restrict__ dst = z ? dst1 : dst0;
  int2* __restrict__ recs = z ? recs1 : recs0;
  int t = threadIdx.x;
  for (int i = t; i < NBK; i += 256) lcnt[i] = 0;
  __syncthreads();
  int base = blockIdx.x * CH;
#pragma unroll 4
  for (int k = 0; k < CH / 256; ++k) {
    int i = base + k * 256 + t;
    if (i < E) atomicAdd(&lcnt[dst[i] >> 6], 1);
  }
  __syncthreads();
  for (int i = t; i < NBK; i += 256) {
    int c = lcnt[i];
    lcnt[i] = c ? atomicAdd(&gcur[(size_t)z * NBK + i], c) : 0;
  }
  __syncthreads();
#pragma unroll 4
  for (int k = 0; k < CH / 256; ++k) {
    int i = base + k * 256 + t;
    if (i < E) {
      int d = dst[i], s = src[i];
      int bin = d >> 6, dl = d & 63;
      int pos = atomicAdd(&lcnt[bin], 1);
      recs[pos] = make_int2(i | (bin << 21), s | (dl << 26));
    }
  }
}

// ---- phase B: in-bucket counting sort by dl, IN PLACE (bucket region is block-exclusive) ----
__global__ __launch_bounds__(256) void sortB_kernel(int2* __restrict__ recs0, int2* __restrict__ recs1,
                                                    const int* __restrict__ cursor,
                                                    const int* __restrict__ counts, int NBK) {
  __shared__ int cnt_lds[64];
  __shared__ int cur_lds[64];
  int z = blockIdx.y;
  int b = blockIdx.x;
  int2* __restrict__ recs = z ? recs1 : recs0;
  int start = cursor[(size_t)z * NBK + b];
  int cnt = counts[(size_t)z * NBK + b];
  int t = threadIdx.x;

  for (int cbase = 0; cbase < cnt; cbase += 2048) {
    int ccnt = min(2048, cnt - cbase);
    int2 r[8];
    int dl[8];
    if (t < 64) cnt_lds[t] = 0;
    __syncthreads();
#pragma unroll
    for (int k = 0; k < 8; ++k) {
      int idx = k * 256 + t;
      if (idx < ccnt) {
        r[k] = recs[start + cbase + idx];
        dl[k] = ((unsigned)r[k].y) >> 26;
        atomicAdd(&cnt_lds[dl[k]], 1);
      }
    }
    __syncthreads();
    if (t < 64) {  // wave 0: exclusive prefix over 64 bins
      int c = cnt_lds[t];
      int x = c;
#pragma unroll
      for (int off = 1; off < 64; off <<= 1) {
        int y = __shfl_up(x, off);
        if (t >= off) x += y;
      }
      cur_lds[t] = x - c;
    }
    __syncthreads();
#pragma unroll
    for (int k = 0; k < 8; ++k) {
      int idx = k * 256 + t;
      if (idx < ccnt) {
        int pos = atomicAdd(&cur_lds[dl[k]], 1);
        recs[start + cbase + pos] = r[k];
      }
    }
    __syncthreads();
  }
}

// ---- edge GEMM over dst-sorted tiles (round-3 structure, packed recs input) ----
// x = e@We + Psrc[src] + b  (bf16, staged in LDS); flush: agg[dst] += relu(x + Pdst[dst])
__global__ __launch_bounds__(256) void edge_sorted_kernel(
    const float* __restrict__ e, const int2* __restrict__ recs,
    const float* __restrict__ W, const float* __restrict__ bmsg,
    const unsigned short* __restrict__ Psrc, const unsigned short* __restrict__ Pdst,
    float* __restrict__ agg, int E) {
  __shared__ unsigned short x_lds[4][64 * XST];

  int lane = threadIdx.x & 63;
  int wv = threadIdx.x >> 6;
  int base = (blockIdx.x * 4 + wv) * 64;
  if (base >= E) return;  // no barriers anywhere: per-wave exit is safe
  int l15 = lane & 15, lh = lane >> 4;
  unsigned short* xw = &x_lds[wv][0];

  // this wave's 64 sorted slots (one coalesced 8B load)
  int slot = base + lane;
  int el = 0, sl = 0, dl = -1;
  if (slot < E) {
    int2 rc = recs[slot];
    el = rc.x & 0x1FFFFF;
    sl = rc.y & 0x3FFFFFF;
    dl = (((rc.x >> 21) & 0x7FF) << 6) | (int)(((unsigned)rc.y) >> 26);
  }

  // ---- Psrc gather: 8 wide dwordx4 instrs; lane covers row i*8+(lane>>3), chunk (lane&7)
  int myrow8 = lane >> 3, mychunk = lane & 7;
  ushort8 psv[8];
#pragma unroll
  for (int i = 0; i < 8; ++i) {
    int srow = __shfl(sl, i * 8 + myrow8);
    psv[i] = *reinterpret_cast<const ushort8*>(Psrc + ((size_t)srow << 6) + mychunk * 8);
  }
  // stage to LDS (releases psv registers before MFMA)
#pragma unroll
  for (int i = 0; i < 8; ++i)
    *reinterpret_cast<ushort8*>(xw + (i * 8 + myrow8) * XST + mychunk * 8) = psv[i];

  short8 bfr[2][4];
  load_bfrags(W, bfr, lane);

  f32x4 acc[4][4];
#pragma unroll
  for (int rt = 0; rt < 4; ++rt)
#pragma unroll
    for (int ct = 0; ct < 4; ++ct) acc[rt][ct] = (f32x4){0.f, 0.f, 0.f, 0.f};

#pragma unroll
  for (int rt = 0; rt < 4; ++rt) {
    int er = __shfl(el, rt * 16 + l15);
    const fvec4* pr = reinterpret_cast<const fvec4*>(e + ((size_t)er << 6));
#pragma unroll
    for (int ks = 0; ks < 2; ++ks) {
      short8 a = cvt8(pr[ks * 8 + lh * 2], pr[ks * 8 + lh * 2 + 1]);
#pragma unroll
      for (int ct = 0; ct < 4; ++ct)
        acc[rt][ct] = __builtin_amdgcn_mfma_f32_16x16x32_bf16(a, bfr[ks][ct], acc[rt][ct], 0, 0, 0);
    }
  }

  float bv[4];
#pragma unroll
  for (int ct = 0; ct < 4; ++ct) bv[ct] = bmsg[ct * 16 + l15];

  // order LDS: ps writes complete & visible before epilogue reads (cross-lane)
  asm volatile("s_waitcnt lgkmcnt(0)" ::: "memory");
  __builtin_amdgcn_sched_barrier(0);

  // ---- epilogue: x = bf16(acc + ps + b), in place
#pragma unroll
  for (int rt = 0; rt < 4; ++rt)
#pragma unroll
    for (int rg = 0; rg < 4; ++rg) {
      int row = rt * 16 + lh * 4 + rg;
#pragma unroll
      for (int ct = 0; ct < 4; ++ct) {
        int c = ct * 16 + l15;
        float v = acc[rt][ct][rg] + bf2f(xw[row * XST + c]) + bv[ct];
        xw[row * XST + c] = f2bf(v);
      }
    }

  asm volatile("s_waitcnt lgkmcnt(0)" ::: "memory");
  __builtin_amdgcn_sched_barrier(0);

  // ---- segmented flush: boundaries precomputed via ballot (SGPR mask)
  int dprev = __shfl_up(dl, 1);
  unsigned long long bnd = __ballot(lane > 0 && dl != dprev);

  float racc = 0.f, pdv = 0.f;
  int dcur = -1;
  for (int r = 0; r < 64; ++r) {
    bool newseg = (r == 0) || ((bnd >> r) & 1ull);
    if (newseg) {  // wave-uniform scalar branch
      if (dcur >= 0) atomicAdd(&agg[(size_t)dcur * 64 + lane], racc);
      dcur = __shfl(dl, r);
      if (dcur < 0) break;  // padding tail (sorted => only at end)
      racc = 0.f;
      pdv = bf2f(Pdst[(size_t)dcur * 64 + lane]);  // one 128B row per segment
    }
    float xv = bf2f(xw[r * XST + lane]);
    racc += fmaxf(xv + pdv, 0.f);
  }
  if (dcur >= 0) atomicAdd(&agg[(size_t)dcur * 64 + lane], racc);
}

struct NodeArgs {
  const float* agg[2];
  const unsigned short* T[2];
  const float* W[2];
  const float* bn[2];
  unsigned short* U[2];
};

// U = bf16(relu(T + agg@Wagg + b_node)); agg split hi+lo bf16 for accuracy
__global__ __launch_bounds__(256) void node_kernel(NodeArgs na, int N) {
  int z = blockIdx.y;
  const float* __restrict__ agg = na.agg[z];
  const unsigned short* __restrict__ T = na.T[z];
  const float* __restrict__ bn = na.bn[z];
  unsigned short* __restrict__ U = na.U[z];
  int lane = threadIdx.x & 63;
  int wv = threadIdx.x >> 6;
  int rowbase = blockIdx.x * 256 + wv * 64;
  int l15 = lane & 15, lh = lane >> 4;

  short8 bfr[2][4];
  load_bfrags(na.W[z], bfr, lane);

  f32x4 acc[4][4];
#pragma unroll
  for (int rt = 0; rt < 4; ++rt)
#pragma unroll
    for (int ct = 0; ct < 4; ++ct) acc[rt][ct] = (f32x4){0.f, 0.f, 0.f, 0.f};

#pragma unroll
  for (int rt = 0; rt < 4; ++rt) {
    int row = rowbase + rt * 16 + l15;
    int rc = row < N ? row : 0;
    const fvec4* p = reinterpret_cast<const fvec4*>(agg + (size_t)rc * 64);
#pragma unroll
    for (int ks = 0; ks < 2; ++ks) {
      fvec4 p0 = p[ks * 8 + lh * 2], p1 = p[ks * 8 + lh * 2 + 1];
      short8 ahi = cvt8(p0, p1);
      fvec4 q0, q1;
#pragma unroll
      for (int i = 0; i < 4; ++i) {
        q0[i] = p0[i] - bf2f((unsigned short)ahi[i]);
        q1[i] = p1[i] - bf2f((unsigned short)ahi[i + 4]);
      }
      short8 alo = cvt8(q0, q1);
#pragma unroll
      for (int ct = 0; ct < 4; ++ct) {
        acc[rt][ct] = __builtin_amdgcn_mfma_f32_16x16x32_bf16(ahi, bfr[ks][ct], acc[rt][ct], 0, 0, 0);
        acc[rt][ct] = __builtin_amdgcn_mfma_f32_16x16x32_bf16(alo, bfr[ks][ct], acc[rt][ct], 0, 0, 0);
      }
    }
  }

  float bv[4];
#pragma unroll
  for (int ct = 0; ct < 4; ++ct) bv[ct] = bn[ct * 16 + l15];

#pragma unroll
  for (int rt = 0; rt < 4; ++rt)
#pragma unroll
    for (int rg = 0; rg < 4; ++rg) {
      int row = rowbase + rt * 16 + lh * 4 + rg;
      if (row < N) {
#pragma unroll
        for (int ct = 0; ct < 4; ++ct) {
          int c = ct * 16 + l15;
          float v = acc[rt][ct][rg] + bf2f(T[(size_t)row * 64 + c]) + bv[ct];
          U[(size_t)row * 64 + c] = f2bf(fmaxf(v, 0.0f));
        }
      }
    }
}

// attention over the 2-way stack; 4 threads per node
__global__ __launch_bounds__(256) void attn_kernel(
    const unsigned short* __restrict__ U0, const unsigned short* __restrict__ U1,
    const float* __restrict__ l1w, const float* __restrict__ l1b, const float* __restrict__ l2w,
    float* __restrict__ out, int N) {
  int t = threadIdx.x;
  int node = blockIdx.x * 64 + (t >> 2);
  int q = t & 3;
  if (node >= N) return;
  size_t b0 = (size_t)node * 64;

  float a0[8], a1[8];
#pragma unroll
  for (int i = 0; i < 8; ++i) { a0[i] = l1b[q * 8 + i]; a1[i] = a0[i]; }

  for (int k = 0; k < 64; ++k) {
    float u0 = bf2f(U0[b0 + k]);
    float u1 = bf2f(U1[b0 + k]);
#pragma unroll
    for (int i = 0; i < 8; ++i) {
      float w = l1w[k * 32 + q * 8 + i];
      a0[i] += u0 * w;
      a1[i] += u1 * w;
    }
  }
  float w0 = 0.f, w1 = 0.f;
#pragma unroll
  for (int i = 0; i < 8; ++i) {
    float l2 = l2w[q * 8 + i];
    w0 += tanhf(a0[i]) * l2;
    w1 += tanhf(a1[i]) * l2;
  }
  w0 += __shfl_xor(w0, 1, 4); w0 += __shfl_xor(w0, 2, 4);
  w1 += __shfl_xor(w1, 1, 4); w1 += __shfl_xor(w1, 2, 4);

  float m = fmaxf(w0, w1);
  float e0 = expf(w0 - m), e1 = expf(w1 - m);
  float inv = 1.0f / (e0 + e1);
  float be0 = e0 * inv, be1 = e1 * inv;

#pragma unroll
  for (int j = 0; j < 16; ++j) {
    int c = q * 16 + j;
    out[b0 + c] = be0 * bf2f(U0[b0 + c]) + be1 * bf2f(U1[b0 + c]);
  }
}

static inline size_t au(size_t x) { return (x + 255) & ~(size_t)255; }

extern "C" void kernel_launch(void* const* d_in, const int* in_sizes, int n_in,
                              void* d_out, int out_size, void* d_ws, size_t ws_size,
                              hipStream_t stream) {
  const float* h      = (const float*)d_in[0];
  const float* e_od   = (const float*)d_in[1];
  const float* e_ad   = (const float*)d_in[2];
  const int* src_od   = (const int*)d_in[3];
  const int* dst_od   = (const int*)d_in[4];
  const int* src_ad   = (const int*)d_in[5];
  const int* dst_ad   = (const int*)d_in[6];
  const float* W_src  = (const float*)d_in[7];
  const float* W_dst  = (const float*)d_in[8];
  const float* W_edge = (const float*)d_in[9];
  const float* b_msg  = (const float*)d_in[10];
  const float* W_self = (const float*)d_in[11];
  const float* W_agg  = (const float*)d_in[12];
  const float* b_node = (const float*)d_in[13];
  const float* l1w    = (const float*)d_in[14];
  const float* l1b    = (const float*)d_in[15];
  const float* l2w    = (const float*)d_in[16];
  float* out = (float*)d_out;

  int N = in_sizes[0] / 64;
  int E = in_sizes[1] / 64;
  int NBK = (N + 63) >> 6;  // 64-node dst buckets

  char* ws = (char*)d_ws;
  size_t off = 0;
  int* counts = (int*)(ws + off);   off += au((size_t)2 * NBK * sizeof(int));
  float* agg0 = (float*)(ws + off); off += (size_t)N * 64 * sizeof(float);
  float* agg1 = (float*)(ws + off); off += (size_t)N * 64 * sizeof(float);
  size_t zero_bytes = off;          // counts + agg0 + agg1 contiguous
  int* cursor = (int*)(ws + off);   off += au((size_t)2 * NBK * sizeof(int));
  int* gcur   = (int*)(ws + off);   off += au((size_t)2 * NBK * sizeof(int));
  int2* recs0 = (int2*)(ws + off);  off += au((size_t)E * sizeof(int2));
  int2* recs1 = (int2*)(ws + off);  off += au((size_t)E * sizeof(int2));
  size_t NP = au((size_t)N * 64 * sizeof(unsigned short));
  unsigned short* Psrc0 = (unsigned short*)(ws + off); off += NP;
  unsigned short* Pdst0 = (unsigned short*)(ws + off); off += NP;
  unsigned short* Psrc1 = (unsigned short*)(ws + off); off += NP;
  unsigned short* Pdst1 = (unsigned short*)(ws + off); off += NP;
  unsigned short* T0    = (unsigned short*)(ws + off); off += NP;
  unsigned short* T1    = (unsigned short*)(ws + off); off += NP;
  unsigned short* U0 = Psrc0;  // dead after edge pass of graph 0
  unsigned short* U1 = Psrc1;  // dead after edge pass of graph 1

  hipMemsetAsync(ws, 0, zero_bytes, stream);

  int nb = (N + 255) / 256;
  ProjArgs pa;
  pa.W[0] = W_src;         pa.out[0] = Psrc0;
  pa.W[1] = W_dst;         pa.out[1] = Pdst0;
  pa.W[2] = W_src + 4096;  pa.out[2] = Psrc1;
  pa.W[3] = W_dst + 4096;  pa.out[3] = Pdst1;
  pa.W[4] = W_self;        pa.out[4] = T0;
  pa.W[5] = W_self + 4096; pa.out[5] = T1;
  proj_all_kernel<<<nb, 256, 0, stream>>>(h, pa, N);

  int nch = (E + CH - 1) / CH;
  hist_kernel<<<dim3(nch, 2), 256, 0, stream>>>(dst_od, dst_ad, counts, E, NBK);
  scan_kernel<<<2, 1024, 0, stream>>>(counts, cursor, gcur, NBK);
  scatterA_kernel<<<dim3(nch, 2), 256, 0, stream>>>(src_od, dst_od, src_ad, dst_ad, gcur,
                                                    recs0, recs1, E, NBK);
  sortB_kernel<<<dim3(NBK, 2), 256, 0, stream>>>(recs0, recs1, cursor, counts, NBK);

  int tiles = (E + 63) / 64;
  int eb = (tiles + 3) / 4;
  edge_sorted_kernel<<<eb, 256, 0, stream>>>(e_od, recs0, W_edge, b_msg,
                                             Psrc0, Pdst0, agg0, E);
  edge_sorted_kernel<<<eb, 256, 0, stream>>>(e_ad, recs1, W_edge + 4096, b_msg + 64,
                                             Psrc1, Pdst1, agg1, E);

  NodeArgs na;
  na.agg[0] = agg0; na.T[0] = T0; na.W[0] = W_agg;        na.bn[0] = b_node;      na.U[0] = U0;
  na.agg[1] = agg1; na.T[1] = T1; na.W[1] = W_agg + 4096; na.bn[1] = b_node + 64; na.U[1] = U1;
  node_kernel<<<dim3(nb, 2), 256, 0, stream>>>(na, N);

  attn_kernel<<<(N + 63) / 64, 256, 0, stream>>>(U0, U1, l1w, l1b, l2w, out, N);
}

// Round 6
// 530.159 us; speedup vs baseline: 2.8059x; 1.2638x over previous
//
#include <hip/hip_runtime.h>
#include <hip/hip_bf16.h>

using short8  = __attribute__((ext_vector_type(8))) short;
using ushort8 = __attribute__((ext_vector_type(8))) unsigned short;
using f32x4   = __attribute__((ext_vector_type(4))) float;
using fvec4   = __attribute__((ext_vector_type(4))) float;

#define CH 8192   // edges per hist/scatter block
#define XST 72    // x LDS row stride in shorts (144B, 16B-aligned)

__device__ inline unsigned short f2bf(float x) {
  union { __hip_bfloat16 b; unsigned short u; } c;
  c.b = __float2bfloat16(x);
  return c.u;
}
__device__ inline float bf2f(unsigned short s) {
  return __uint_as_float(((unsigned int)s) << 16);
}
__device__ inline unsigned int pk2(float lo, float hi) {
  union { __hip_bfloat162 b; unsigned int u; } c;
  c.b = __float22bfloat162_rn(make_float2(lo, hi));
  return c.u;
}
// 8 f32 -> short8 of bf16 via v_cvt_pk_bf16_f32
__device__ inline short8 cvt8(fvec4 a, fvec4 b) {
  union { short8 s; unsigned int u[4]; } r;
  r.u[0] = pk2(a[0], a[1]);
  r.u[1] = pk2(a[2], a[3]);
  r.u[2] = pk2(b[0], b[1]);
  r.u[3] = pk2(b[2], b[3]);
  return r.s;
}

// B fragments for [64x64] W (row-major f32): lane holds B[k=ks*32+lh*8+i][col=ct*16+l15]
__device__ inline void load_bfrags_f32(const float* __restrict__ W, short8 bfr[2][4], int lane) {
  int l15 = lane & 15, lh = lane >> 4;
#pragma unroll
  for (int ks = 0; ks < 2; ++ks)
#pragma unroll
    for (int ct = 0; ct < 4; ++ct) {
      short8 v;
#pragma unroll
      for (int i = 0; i < 8; ++i)
        v[i] = (short)f2bf(W[(ks * 32 + lh * 8 + i) * 64 + ct * 16 + l15]);
      bfr[ks][ct] = v;
    }
}

// pre-fragmented bf16 W: frag (ks,ct) for lane at Wf[((ks*4+ct)<<9) + (lane<<3)]
__device__ inline void load_bfrags(const unsigned short* __restrict__ Wf, short8 bfr[2][4], int lane) {
#pragma unroll
  for (int ks = 0; ks < 2; ++ks)
#pragma unroll
    for (int ct = 0; ct < 4; ++ct) {
      union { ushort8 u; short8 s; } c;
      c.u = *reinterpret_cast<const ushort8*>(Wf + (((ks * 4 + ct) << 9) + (lane << 3)));
      bfr[ks][ct] = c.s;
    }
}

struct PrepArgs {
  const float* W[10];
};

// one-time: convert 10 [64x64] f32 W matrices into MFMA fragment-layout bf16
__global__ __launch_bounds__(64) void prep_w_kernel(PrepArgs pw, unsigned short* __restrict__ Wf) {
  int z = blockIdx.x;
  int lane = threadIdx.x & 63;
  short8 bfr[2][4];
  load_bfrags_f32(pw.W[z], bfr, lane);
  unsigned short* dst = Wf + (size_t)z * 4096;
#pragma unroll
  for (int ks = 0; ks < 2; ++ks)
#pragma unroll
    for (int ct = 0; ct < 4; ++ct) {
      union { short8 s; ushort8 u; } c;
      c.s = bfr[ks][ct];
      *reinterpret_cast<ushort8*>(dst + (((ks * 4 + ct) << 9) + (lane << 3))) = c.u;
    }
}

struct ProjArgs {
  unsigned short* out[6];
};

// all 6 projections of h in one pass (read h once)
__global__ __launch_bounds__(256) void proj_all_kernel(const float* __restrict__ h,
                                                       const unsigned short* __restrict__ Wf,
                                                       ProjArgs pa, int N) {
  int lane = threadIdx.x & 63;
  int wv = threadIdx.x >> 6;
  int rowbase = blockIdx.x * 256 + wv * 64;
  int l15 = lane & 15, lh = lane >> 4;

  short8 afr[4][2];
#pragma unroll
  for (int rt = 0; rt < 4; ++rt) {
    int row = rowbase + rt * 16 + l15;
    int rc = row < N ? row : 0;
    const fvec4* p = reinterpret_cast<const fvec4*>(h + (size_t)rc * 64);
#pragma unroll
    for (int ks = 0; ks < 2; ++ks)
      afr[rt][ks] = cvt8(p[ks * 8 + lh * 2], p[ks * 8 + lh * 2 + 1]);
  }

  for (int z = 0; z < 6; ++z) {
    short8 bfr[2][4];
    load_bfrags(Wf + (size_t)z * 4096, bfr, lane);
    unsigned short* __restrict__ out = pa.out[z];

    f32x4 acc[4][4];
#pragma unroll
    for (int rt = 0; rt < 4; ++rt)
#pragma unroll
      for (int ct = 0; ct < 4; ++ct) acc[rt][ct] = (f32x4){0.f, 0.f, 0.f, 0.f};

#pragma unroll
    for (int rt = 0; rt < 4; ++rt)
#pragma unroll
      for (int ks = 0; ks < 2; ++ks)
#pragma unroll
        for (int ct = 0; ct < 4; ++ct)
          acc[rt][ct] = __builtin_amdgcn_mfma_f32_16x16x32_bf16(afr[rt][ks], bfr[ks][ct], acc[rt][ct], 0, 0, 0);

#pragma unroll
    for (int rt = 0; rt < 4; ++rt)
#pragma unroll
      for (int rg = 0; rg < 4; ++rg) {
        int row = rowbase + rt * 16 + lh * 4 + rg;
        if (row < N) {
#pragma unroll
          for (int ct = 0; ct < 4; ++ct)
            out[(size_t)row * 64 + ct * 16 + l15] = f2bf(acc[rt][ct][rg]);
        }
      }
  }
}

// ---- bucket histogram (bin = dst>>6), LDS-aggregated ----
__global__ __launch_bounds__(256) void hist_kernel(const int* __restrict__ dst0, const int* __restrict__ dst1,
                                                   int* __restrict__ counts, int E, int NBK) {
  __shared__ int hcnt[2048];
  int z = blockIdx.y;
  const int* __restrict__ dst = z ? dst1 : dst0;
  int t = threadIdx.x;
  for (int i = t; i < NBK; i += 256) hcnt[i] = 0;
  __syncthreads();
  int base = blockIdx.x * CH;
#pragma unroll 4
  for (int k = 0; k < CH / 256; ++k) {
    int i = base + k * 256 + t;
    if (i < E) atomicAdd(&hcnt[dst[i] >> 6], 1);
  }
  __syncthreads();
  for (int i = t; i < NBK; i += 256) {
    int c = hcnt[i];
    if (c) atomicAdd(&counts[(size_t)z * NBK + i], c);
  }
}

// exclusive scan of bucket counts -> cursor (preserved) and gcur (working copy)
__global__ __launch_bounds__(1024) void scan_kernel(const int* __restrict__ counts, int* __restrict__ cursor,
                                                    int* __restrict__ gcur, int NBK) {
  int z = blockIdx.x;
  const int* c = counts + (size_t)z * NBK;
  __shared__ int lds[1024];
  int t = threadIdx.x;
  int carry = 0;
  for (int base = 0; base < NBK; base += 1024) {
    int i = base + t;
    int v = (i < NBK) ? c[i] : 0;
    lds[t] = v;
    __syncthreads();
    for (int off = 1; off < 1024; off <<= 1) {
      int x = (t >= off) ? lds[t - off] : 0;
      __syncthreads();
      lds[t] += x;
      __syncthreads();
    }
    if (i < NBK) {
      int excl = carry + lds[t] - v;
      cursor[(size_t)z * NBK + i] = excl;
      gcur[(size_t)z * NBK + i] = excl;
    }
    carry += lds[1023];
    __syncthreads();
  }
}

// ---- phase A: bucket scatter with per-block rank aggregation ----
// packed record: x = el | (bin<<21)   (el<2^21, bin<2^11)
//                y = src | (dl<<26)   (src<2^26, dl<64)
__global__ __launch_bounds__(256) void scatterA_kernel(
    const int* __restrict__ src0, const int* __restrict__ dst0,
    const int* __restrict__ src1, const int* __restrict__ dst1,
    int* __restrict__ gcur, int2* __restrict__ recs0, int2* __restrict__ recs1,
    int E, int NBK) {
  __shared__ int lcnt[2048];
  int z = blockIdx.y;
  const int* __restrict__ src = z ? src1 : src0;
  const int* __restrict__ dst = z ? dst1 : dst0;
  int2* __restrict__ recs = z ? recs1 : recs0;
  int t = threadIdx.x;
  for (int i = t; i < NBK; i += 256) lcnt[i] = 0;
  __syncthreads();
  int base = blockIdx.x * CH;
#pragma unroll 4
  for (int k = 0; k < CH / 256; ++k) {
    int i = base + k * 256 + t;
    if (i < E) atomicAdd(&lcnt[dst[i] >> 6], 1);
  }
  __syncthreads();
  for (int i = t; i < NBK; i += 256) {
    int c = lcnt[i];
    lcnt[i] = c ? atomicAdd(&gcur[(size_t)z * NBK + i], c) : 0;
  }
  __syncthreads();
#pragma unroll 4
  for (int k = 0; k < CH / 256; ++k) {
    int i = base + k * 256 + t;
    if (i < E) {
      int d = dst[i], s = src[i];
      int bin = d >> 6, dl = d & 63;
      int pos = atomicAdd(&lcnt[bin], 1);
      recs[pos] = make_int2(i | (bin << 21), s | (dl << 26));
    }
  }
}

// ---- phase B: in-bucket counting sort by dl, IN PLACE (bucket region is block-exclusive) ----
__global__ __launch_bounds__(256) void sortB_kernel(int2* __restrict__ recs0, int2* __restrict__ recs1,
                                                    const int* __restrict__ cursor,
                                                    const int* __restrict__ counts, int NBK) {
  __shared__ int cnt_lds[64];
  __shared__ int cur_lds[64];
  int z = blockIdx.y;
  int b = blockIdx.x;
  int2* __restrict__ recs = z ? recs1 : recs0;
  int start = cursor[(size_t)z * NBK + b];
  int cnt = counts[(size_t)z * NBK + b];
  int t = threadIdx.x;

  for (int cbase = 0; cbase < cnt; cbase += 2048) {
    int ccnt = min(2048, cnt - cbase);
    int2 r[8];
    int dl[8];
    if (t < 64) cnt_lds[t] = 0;
    __syncthreads();
#pragma unroll
    for (int k = 0; k < 8; ++k) {
      int idx = k * 256 + t;
      if (idx < ccnt) {
        r[k] = recs[start + cbase + idx];
        dl[k] = ((unsigned)r[k].y) >> 26;
        atomicAdd(&cnt_lds[dl[k]], 1);
      }
    }
    __syncthreads();
    if (t < 64) {  // wave 0: exclusive prefix over 64 bins
      int c = cnt_lds[t];
      int x = c;
#pragma unroll
      for (int off = 1; off < 64; off <<= 1) {
        int y = __shfl_up(x, off);
        if (t >= off) x += y;
      }
      cur_lds[t] = x - c;
    }
    __syncthreads();
#pragma unroll
    for (int k = 0; k < 8; ++k) {
      int idx = k * 256 + t;
      if (idx < ccnt) {
        int pos = atomicAdd(&cur_lds[dl[k]], 1);
        recs[start + cbase + pos] = r[k];
      }
    }
    __syncthreads();
  }
}

// ---- edge GEMM over dst-sorted tiles ----
// x = e@We + Psrc[src] + b  (bf16, staged in LDS); flush: agg[dst] += relu(x + Pdst[dst])
__global__ __launch_bounds__(256) void edge_sorted_kernel(
    const float* __restrict__ e, const int2* __restrict__ recs,
    const unsigned short* __restrict__ Wf, const float* __restrict__ bmsg,
    const unsigned short* __restrict__ Psrc, const unsigned short* __restrict__ Pdst,
    float* __restrict__ agg, int E) {
  __shared__ unsigned short x_lds[4][64 * XST];

  int lane = threadIdx.x & 63;
  int wv = threadIdx.x >> 6;
  int base = (blockIdx.x * 4 + wv) * 64;
  if (base >= E) return;  // no barriers anywhere: per-wave exit is safe
  int l15 = lane & 15, lh = lane >> 4;
  unsigned short* xw = &x_lds[wv][0];

  // this wave's 64 sorted slots (one coalesced 8B load)
  int slot = base + lane;
  int el = 0, sl = 0, dl = 0;
  if (slot < E) {
    int2 rc = recs[slot];
    el = rc.x & 0x1FFFFF;
    sl = rc.y & 0x3FFFFFF;
    dl = (((rc.x >> 21) & 0x7FF) << 6) | (int)(((unsigned)rc.y) >> 26);
  }

  // ---- Psrc gather: 8 wide dwordx4 instrs; lane covers row i*8+(lane>>3), chunk (lane&7)
  int myrow8 = lane >> 3, mychunk = lane & 7;
  ushort8 psv[8];
#pragma unroll
  for (int i = 0; i < 8; ++i) {
    int srow = __shfl(sl, i * 8 + myrow8);
    psv[i] = *reinterpret_cast<const ushort8*>(Psrc + ((size_t)srow << 6) + mychunk * 8);
  }
  // stage to LDS (releases psv registers before MFMA)
#pragma unroll
  for (int i = 0; i < 8; ++i)
    *reinterpret_cast<ushort8*>(xw + (i * 8 + myrow8) * XST + mychunk * 8) = psv[i];

  short8 bfr[2][4];
  load_bfrags(Wf, bfr, lane);

  f32x4 acc[4][4];
#pragma unroll
  for (int rt = 0; rt < 4; ++rt)
#pragma unroll
    for (int ct = 0; ct < 4; ++ct) acc[rt][ct] = (f32x4){0.f, 0.f, 0.f, 0.f};

#pragma unroll
  for (int rt = 0; rt < 4; ++rt) {
    int er = __shfl(el, rt * 16 + l15);
    const fvec4* pr = reinterpret_cast<const fvec4*>(e + ((size_t)er << 6));
#pragma unroll
    for (int ks = 0; ks < 2; ++ks) {
      short8 a = cvt8(pr[ks * 8 + lh * 2], pr[ks * 8 + lh * 2 + 1]);
#pragma unroll
      for (int ct = 0; ct < 4; ++ct)
        acc[rt][ct] = __builtin_amdgcn_mfma_f32_16x16x32_bf16(a, bfr[ks][ct], acc[rt][ct], 0, 0, 0);
    }
  }

  float bv[4];
#pragma unroll
  for (int ct = 0; ct < 4; ++ct) bv[ct] = bmsg[ct * 16 + l15];

  // order LDS: ps writes complete & visible before epilogue reads (cross-lane)
  asm volatile("s_waitcnt lgkmcnt(0)" ::: "memory");
  __builtin_amdgcn_sched_barrier(0);

  // ---- epilogue: x = bf16(acc + ps + b), in place
#pragma unroll
  for (int rt = 0; rt < 4; ++rt)
#pragma unroll
    for (int rg = 0; rg < 4; ++rg) {
      int row = rt * 16 + lh * 4 + rg;
#pragma unroll
      for (int ct = 0; ct < 4; ++ct) {
        int c = ct * 16 + l15;
        float v = acc[rt][ct][rg] + bf2f(xw[row * XST + c]) + bv[ct];
        xw[row * XST + c] = f2bf(v);
      }
    }

  asm volatile("s_waitcnt lgkmcnt(0)" ::: "memory");
  __builtin_amdgcn_sched_barrier(0);

  // ---- segmented flush: boundaries precomputed via ballot (SGPR mask)
  int dprev = __shfl_up(dl, 1);
  unsigned long long bnd = __ballot(lane > 0 && dl != dprev);
  int vrows = min(64, E - base);  // wave-uniform; rows >= vrows are padding

  float racc = 0.f, pdv = 0.f;
  int dcur = -1;
#pragma unroll 4
  for (int r = 0; r < vrows; ++r) {
    bool newseg = (r == 0) || ((bnd >> r) & 1ull);
    if (newseg) {  // wave-uniform scalar branch
      if (dcur >= 0) atomicAdd(&agg[(size_t)dcur * 64 + lane], racc);
      dcur = __shfl(dl, r);
      racc = 0.f;
      pdv = bf2f(Pdst[(size_t)dcur * 64 + lane]);  // one 128B row per segment
    }
    racc += fmaxf(bf2f(xw[r * XST + lane]) + pdv, 0.f);
  }
  if (dcur >= 0) atomicAdd(&agg[(size_t)dcur * 64 + lane], racc);
}

struct NodeArgs {
  const float* agg[2];
  const unsigned short* T[2];
  const float* bn[2];
  unsigned short* U[2];
};

// U = bf16(relu(T + agg@Wagg + b_node)); agg split hi+lo bf16 for accuracy
__global__ __launch_bounds__(256) void node_kernel(const unsigned short* __restrict__ Wf,
                                                   NodeArgs na, int N) {
  int z = blockIdx.y;
  const float* __restrict__ agg = na.agg[z];
  const unsigned short* __restrict__ T = na.T[z];
  const float* __restrict__ bn = na.bn[z];
  unsigned short* __restrict__ U = na.U[z];
  int lane = threadIdx.x & 63;
  int wv = threadIdx.x >> 6;
  int rowbase = blockIdx.x * 256 + wv * 64;
  int l15 = lane & 15, lh = lane >> 4;

  short8 bfr[2][4];
  load_bfrags(Wf + (size_t)(8 + z) * 4096, bfr, lane);

  f32x4 acc[4][4];
#pragma unroll
  for (int rt = 0; rt < 4; ++rt)
#pragma unroll
    for (int ct = 0; ct < 4; ++ct) acc[rt][ct] = (f32x4){0.f, 0.f, 0.f, 0.f};

#pragma unroll
  for (int rt = 0; rt < 4; ++rt) {
    int row = rowbase + rt * 16 + l15;
    int rc = row < N ? row : 0;
    const fvec4* p = reinterpret_cast<const fvec4*>(agg + (size_t)rc * 64);
#pragma unroll
    for (int ks = 0; ks < 2; ++ks) {
      fvec4 p0 = p[ks * 8 + lh * 2], p1 = p[ks * 8 + lh * 2 + 1];
      short8 ahi = cvt8(p0, p1);
      fvec4 q0, q1;
#pragma unroll
      for (int i = 0; i < 4; ++i) {
        q0[i] = p0[i] - bf2f((unsigned short)ahi[i]);
        q1[i] = p1[i] - bf2f((unsigned short)ahi[i + 4]);
      }
      short8 alo = cvt8(q0, q1);
#pragma unroll
      for (int ct = 0; ct < 4; ++ct) {
        acc[rt][ct] = __builtin_amdgcn_mfma_f32_16x16x32_bf16(ahi, bfr[ks][ct], acc[rt][ct], 0, 0, 0);
        acc[rt][ct] = __builtin_amdgcn_mfma_f32_16x16x32_bf16(alo, bfr[ks][ct], acc[rt][ct], 0, 0, 0);
      }
    }
  }

  float bv[4];
#pragma unroll
  for (int ct = 0; ct < 4; ++ct) bv[ct] = bn[ct * 16 + l15];

#pragma unroll
  for (int rt = 0; rt < 4; ++rt)
#pragma unroll
    for (int rg = 0; rg < 4; ++rg) {
      int row = rowbase + rt * 16 + lh * 4 + rg;
      if (row < N) {
#pragma unroll
        for (int ct = 0; ct < 4; ++ct) {
          int c = ct * 16 + l15;
          float v = acc[rt][ct][rg] + bf2f(T[(size_t)row * 64 + c]) + bv[ct];
          U[(size_t)row * 64 + c] = f2bf(fmaxf(v, 0.0f));
        }
      }
    }
}

// attention over the 2-way stack; 4 threads per node
__global__ __launch_bounds__(256) void attn_kernel(
    const unsigned short* __restrict__ U0, const unsigned short* __restrict__ U1,
    const float* __restrict__ l1w, const float* __restrict__ l1b, const float* __restrict__ l2w,
    float* __restrict__ out, int N) {
  int t = threadIdx.x;
  int node = blockIdx.x * 64 + (t >> 2);
  int q = t & 3;
  if (node >= N) return;
  size_t b0 = (size_t)node * 64;

  float a0[8], a1[8];
#pragma unroll
  for (int i = 0; i < 8; ++i) { a0[i] = l1b[q * 8 + i]; a1[i] = a0[i]; }

  for (int k = 0; k < 64; ++k) {
    float u0 = bf2f(U0[b0 + k]);
    float u1 = bf2f(U1[b0 + k]);
#pragma unroll
    for (int i = 0; i < 8; ++i) {
      float w = l1w[k * 32 + q * 8 + i];
      a0[i] += u0 * w;
      a1[i] += u1 * w;
    }
  }
  float w0 = 0.f, w1 = 0.f;
#pragma unroll
  for (int i = 0; i < 8; ++i) {
    float l2 = l2w[q * 8 + i];
    w0 += tanhf(a0[i]) * l2;
    w1 += tanhf(a1[i]) * l2;
  }
  w0 += __shfl_xor(w0, 1, 4); w0 += __shfl_xor(w0, 2, 4);
  w1 += __shfl_xor(w1, 1, 4); w1 += __shfl_xor(w1, 2, 4);

  float m = fmaxf(w0, w1);
  float e0 = expf(w0 - m), e1 = expf(w1 - m);
  float inv = 1.0f / (e0 + e1);
  float be0 = e0 * inv, be1 = e1 * inv;

#pragma unroll
  for (int j = 0; j < 16; ++j) {
    int c = q * 16 + j;
    out[b0 + c] = be0 * bf2f(U0[b0 + c]) + be1 * bf2f(U1[b0 + c]);
  }
}

static inline size_t au(size_t x) { return (x + 255) & ~(size_t)255; }

extern "C" void kernel_launch(void* const* d_in, const int* in_sizes, int n_in,
                              void* d_out, int out_size, void* d_ws, size_t ws_size,
                              hipStream_t stream) {
  const float* h      = (const float*)d_in[0];
  const float* e_od   = (const float*)d_in[1];
  const float* e_ad   = (const float*)d_in[2];
  const int* src_od   = (const int*)d_in[3];
  const int* dst_od   = (const int*)d_in[4];
  const int* src_ad   = (const int*)d_in[5];
  const int* dst_ad   = (const int*)d_in[6];
  const float* W_src  = (const float*)d_in[7];
  const float* W_dst  = (const float*)d_in[8];
  const float* W_edge = (const float*)d_in[9];
  const float* b_msg  = (const float*)d_in[10];
  const float* W_self = (const float*)d_in[11];
  const float* W_agg  = (const float*)d_in[12];
  const float* b_node = (const float*)d_in[13];
  const float* l1w    = (const float*)d_in[14];
  const float* l1b    = (const float*)d_in[15];
  const float* l2w    = (const float*)d_in[16];
  float* out = (float*)d_out;

  int N = in_sizes[0] / 64;
  int E = in_sizes[1] / 64;
  int NBK = (N + 63) >> 6;  // 64-node dst buckets

  char* ws = (char*)d_ws;
  size_t off = 0;
  int* counts = (int*)(ws + off);   off += au((size_t)2 * NBK * sizeof(int));
  float* agg0 = (float*)(ws + off); off += (size_t)N * 64 * sizeof(float);
  float* agg1 = (float*)(ws + off); off += (size_t)N * 64 * sizeof(float);
  size_t zero_bytes = off;          // counts + agg0 + agg1 contiguous
  int* cursor = (int*)(ws + off);   off += au((size_t)2 * NBK * sizeof(int));
  int* gcur   = (int*)(ws + off);   off += au((size_t)2 * NBK * sizeof(int));
  int2* recs0 = (int2*)(ws + off);  off += au((size_t)E * sizeof(int2));
  int2* recs1 = (int2*)(ws + off);  off += au((size_t)E * sizeof(int2));
  unsigned short* Wf = (unsigned short*)(ws + off); off += au((size_t)10 * 4096 * sizeof(unsigned short));
  size_t NP = au((size_t)N * 64 * sizeof(unsigned short));
  unsigned short* Psrc0 = (unsigned short*)(ws + off); off += NP;
  unsigned short* Pdst0 = (unsigned short*)(ws + off); off += NP;
  unsigned short* Psrc1 = (unsigned short*)(ws + off); off += NP;
  unsigned short* Pdst1 = (unsigned short*)(ws + off); off += NP;
  unsigned short* T0    = (unsigned short*)(ws + off); off += NP;
  unsigned short* T1    = (unsigned short*)(ws + off); off += NP;
  unsigned short* U0 = Psrc0;  // dead after edge pass of graph 0
  unsigned short* U1 = Psrc1;  // dead after edge pass of graph 1

  hipMemsetAsync(ws, 0, zero_bytes, stream);

  // one-time weight prep: fragment-layout bf16 (10 matrices, 1 wave each)
  PrepArgs pw;
  pw.W[0] = W_src;         pw.W[1] = W_dst;
  pw.W[2] = W_src + 4096;  pw.W[3] = W_dst + 4096;
  pw.W[4] = W_self;        pw.W[5] = W_self + 4096;
  pw.W[6] = W_edge;        pw.W[7] = W_edge + 4096;
  pw.W[8] = W_agg;         pw.W[9] = W_agg + 4096;
  prep_w_kernel<<<10, 64, 0, stream>>>(pw, Wf);

  int nb = (N + 255) / 256;
  ProjArgs pa;
  pa.out[0] = Psrc0;
  pa.out[1] = Pdst0;
  pa.out[2] = Psrc1;
  pa.out[3] = Pdst1;
  pa.out[4] = T0;
  pa.out[5] = T1;
  proj_all_kernel<<<nb, 256, 0, stream>>>(h, Wf, pa, N);

  int nch = (E + CH - 1) / CH;
  hist_kernel<<<dim3(nch, 2), 256, 0, stream>>>(dst_od, dst_ad, counts, E, NBK);
  scan_kernel<<<2, 1024, 0, stream>>>(counts, cursor, gcur, NBK);
  scatterA_kernel<<<dim3(nch, 2), 256, 0, stream>>>(src_od, dst_od, src_ad, dst_ad, gcur,
                                                    recs0, recs1, E, NBK);
  sortB_kernel<<<dim3(NBK, 2), 256, 0, stream>>>(recs0, recs1, cursor, counts, NBK);

  int tiles = (E + 63) / 64;
  int eb = (tiles + 3) / 4;
  edge_sorted_kernel<<<eb, 256, 0, stream>>>(e_od, recs0, Wf + 6 * 4096, b_msg,
                                             Psrc0, Pdst0, agg0, E);
  edge_sorted_kernel<<<eb, 256, 0, stream>>>(e_ad, recs1, Wf + 7 * 4096, b_msg + 64,
                                             Psrc1, Pdst1, agg1, E);

  NodeArgs na;
  na.agg[0] = agg0; na.T[0] = T0; na.bn[0] = b_node;      na.U[0] = U0;
  na.agg[1] = agg1; na.T[1] = T1; na.bn[1] = b_node + 64; na.U[1] = U1;
  node_kernel<<<dim3(nb, 2), 256, 0, stream>>>(Wf, na, N);

  attn_kernel<<<(N + 63) / 64, 256, 0, stream>>>(U0, U1, l1w, l1b, l2w, out, N);
}

// Round 7
// 529.499 us; speedup vs baseline: 2.8094x; 1.0012x over previous
//
#include <hip/hip_runtime.h>
#include <hip/hip_bf16.h>

using short8  = __attribute__((ext_vector_type(8))) short;
using ushort8 = __attribute__((ext_vector_type(8))) unsigned short;
using f32x4   = __attribute__((ext_vector_type(4))) float;
using fvec4   = __attribute__((ext_vector_type(4))) float;

#define CH 8192   // edges per hist/scatter block

__device__ inline unsigned short f2bf(float x) {
  union { __hip_bfloat16 b; unsigned short u; } c;
  c.b = __float2bfloat16(x);
  return c.u;
}
__device__ inline float bf2f(unsigned short s) {
  return __uint_as_float(((unsigned int)s) << 16);
}
__device__ inline unsigned int pk2(float lo, float hi) {
  union { __hip_bfloat162 b; unsigned int u; } c;
  c.b = __float22bfloat162_rn(make_float2(lo, hi));
  return c.u;
}
// 8 f32 -> short8 of bf16 via v_cvt_pk_bf16_f32
__device__ inline short8 cvt8(fvec4 a, fvec4 b) {
  union { short8 s; unsigned int u[4]; } r;
  r.u[0] = pk2(a[0], a[1]);
  r.u[1] = pk2(a[2], a[3]);
  r.u[2] = pk2(b[0], b[1]);
  r.u[3] = pk2(b[2], b[3]);
  return r.s;
}

// B fragments for [64x64] W (row-major f32): lane holds B[k=ks*32+lh*8+i][col=ct*16+l15]
__device__ inline void load_bfrags_f32(const float* __restrict__ W, short8 bfr[2][4], int lane) {
  int l15 = lane & 15, lh = lane >> 4;
#pragma unroll
  for (int ks = 0; ks < 2; ++ks)
#pragma unroll
    for (int ct = 0; ct < 4; ++ct) {
      short8 v;
#pragma unroll
      for (int i = 0; i < 8; ++i)
        v[i] = (short)f2bf(W[(ks * 32 + lh * 8 + i) * 64 + ct * 16 + l15]);
      bfr[ks][ct] = v;
    }
}

// pre-fragmented bf16 W: frag (ks,ct) for lane at Wf[((ks*4+ct)<<9) + (lane<<3)]
__device__ inline void load_bfrags(const unsigned short* __restrict__ Wf, short8 bfr[2][4], int lane) {
#pragma unroll
  for (int ks = 0; ks < 2; ++ks)
#pragma unroll
    for (int ct = 0; ct < 4; ++ct) {
      union { ushort8 u; short8 s; } c;
      c.u = *reinterpret_cast<const ushort8*>(Wf + (((ks * 4 + ct) << 9) + (lane << 3)));
      bfr[ks][ct] = c.s;
    }
}

struct PrepArgs {
  const float* W[10];
};

// one-time: convert 10 [64x64] f32 W matrices into MFMA fragment-layout bf16
__global__ __launch_bounds__(64) void prep_w_kernel(PrepArgs pw, unsigned short* __restrict__ Wf) {
  int z = blockIdx.x;
  int lane = threadIdx.x & 63;
  short8 bfr[2][4];
  load_bfrags_f32(pw.W[z], bfr, lane);
  unsigned short* dst = Wf + (size_t)z * 4096;
#pragma unroll
  for (int ks = 0; ks < 2; ++ks)
#pragma unroll
    for (int ct = 0; ct < 4; ++ct) {
      union { short8 s; ushort8 u; } c;
      c.s = bfr[ks][ct];
      *reinterpret_cast<ushort8*>(dst + (((ks * 4 + ct) << 9) + (lane << 3))) = c.u;
    }
}

struct ProjArgs {
  unsigned short* out[6];
};

// all 6 projections of h in one pass (read h once)
__global__ __launch_bounds__(256) void proj_all_kernel(const float* __restrict__ h,
                                                       const unsigned short* __restrict__ Wf,
                                                       ProjArgs pa, int N) {
  int lane = threadIdx.x & 63;
  int wv = threadIdx.x >> 6;
  int rowbase = blockIdx.x * 256 + wv * 64;
  int l15 = lane & 15, lh = lane >> 4;

  short8 afr[4][2];
#pragma unroll
  for (int rt = 0; rt < 4; ++rt) {
    int row = rowbase + rt * 16 + l15;
    int rc = row < N ? row : 0;
    const fvec4* p = reinterpret_cast<const fvec4*>(h + (size_t)rc * 64);
#pragma unroll
    for (int ks = 0; ks < 2; ++ks)
      afr[rt][ks] = cvt8(p[ks * 8 + lh * 2], p[ks * 8 + lh * 2 + 1]);
  }

  for (int z = 0; z < 6; ++z) {
    short8 bfr[2][4];
    load_bfrags(Wf + (size_t)z * 4096, bfr, lane);
    unsigned short* __restrict__ out = pa.out[z];

    f32x4 acc[4][4];
#pragma unroll
    for (int rt = 0; rt < 4; ++rt)
#pragma unroll
      for (int ct = 0; ct < 4; ++ct) acc[rt][ct] = (f32x4){0.f, 0.f, 0.f, 0.f};

#pragma unroll
    for (int rt = 0; rt < 4; ++rt)
#pragma unroll
      for (int ks = 0; ks < 2; ++ks)
#pragma unroll
        for (int ct = 0; ct < 4; ++ct)
          acc[rt][ct] = __builtin_amdgcn_mfma_f32_16x16x32_bf16(afr[rt][ks], bfr[ks][ct], acc[rt][ct], 0, 0, 0);

#pragma unroll
    for (int rt = 0; rt < 4; ++rt)
#pragma unroll
      for (int rg = 0; rg < 4; ++rg) {
        int row = rowbase + rt * 16 + lh * 4 + rg;
        if (row < N) {
#pragma unroll
          for (int ct = 0; ct < 4; ++ct)
            out[(size_t)row * 64 + ct * 16 + l15] = f2bf(acc[rt][ct][rg]);
        }
      }
  }
}

// ---- bucket histogram (bin = dst>>6), LDS-aggregated ----
__global__ __launch_bounds__(256) void hist_kernel(const int* __restrict__ dst0, const int* __restrict__ dst1,
                                                   int* __restrict__ counts, int E, int NBK) {
  __shared__ int hcnt[2048];
  int z = blockIdx.y;
  const int* __restrict__ dst = z ? dst1 : dst0;
  int t = threadIdx.x;
  for (int i = t; i < NBK; i += 256) hcnt[i] = 0;
  __syncthreads();
  int base = blockIdx.x * CH;
#pragma unroll 4
  for (int k = 0; k < CH / 256; ++k) {
    int i = base + k * 256 + t;
    if (i < E) atomicAdd(&hcnt[dst[i] >> 6], 1);
  }
  __syncthreads();
  for (int i = t; i < NBK; i += 256) {
    int c = hcnt[i];
    if (c) atomicAdd(&counts[(size_t)z * NBK + i], c);
  }
}

// exclusive scan of bucket counts -> cursor (preserved) and gcur (working copy)
__global__ __launch_bounds__(1024) void scan_kernel(const int* __restrict__ counts, int* __restrict__ cursor,
                                                    int* __restrict__ gcur, int NBK) {
  int z = blockIdx.x;
  const int* c = counts + (size_t)z * NBK;
  __shared__ int lds[1024];
  int t = threadIdx.x;
  int carry = 0;
  for (int base = 0; base < NBK; base += 1024) {
    int i = base + t;
    int v = (i < NBK) ? c[i] : 0;
    lds[t] = v;
    __syncthreads();
    for (int off = 1; off < 1024; off <<= 1) {
      int x = (t >= off) ? lds[t - off] : 0;
      __syncthreads();
      lds[t] += x;
      __syncthreads();
    }
    if (i < NBK) {
      int excl = carry + lds[t] - v;
      cursor[(size_t)z * NBK + i] = excl;
      gcur[(size_t)z * NBK + i] = excl;
    }
    carry += lds[1023];
    __syncthreads();
  }
}

// ---- phase A: bucket scatter with per-block rank aggregation ----
// packed record: x = el | (bin<<21)   (el<2^21, bin<2^11)
//                y = src | (dl<<26)   (src<2^26, dl<64)
__global__ __launch_bounds__(256) void scatterA_kernel(
    const int* __restrict__ src0, const int* __restrict__ dst0,
    const int* __restrict__ src1, const int* __restrict__ dst1,
    int* __restrict__ gcur, int2* __restrict__ recs0, int2* __restrict__ recs1,
    int E, int NBK) {
  __shared__ int lcnt[2048];
  int z = blockIdx.y;
  const int* __restrict__ src = z ? src1 : src0;
  const int* __restrict__ dst = z ? dst1 : dst0;
  int2* __restrict__ recs = z ? recs1 : recs0;
  int t = threadIdx.x;
  for (int i = t; i < NBK; i += 256) lcnt[i] = 0;
  __syncthreads();
  int base = blockIdx.x * CH;
#pragma unroll 4
  for (int k = 0; k < CH / 256; ++k) {
    int i = base + k * 256 + t;
    if (i < E) atomicAdd(&lcnt[dst[i] >> 6], 1);
  }
  __syncthreads();
  for (int i = t; i < NBK; i += 256) {
    int c = lcnt[i];
    lcnt[i] = c ? atomicAdd(&gcur[(size_t)z * NBK + i], c) : 0;
  }
  __syncthreads();
#pragma unroll 4
  for (int k = 0; k < CH / 256; ++k) {
    int i = base + k * 256 + t;
    if (i < E) {
      int d = dst[i], s = src[i];
      int bin = d >> 6, dl = d & 63;
      int pos = atomicAdd(&lcnt[bin], 1);
      recs[pos] = make_int2(i | (bin << 21), s | (dl << 26));
    }
  }
}

// ---- phase B: in-bucket counting sort by dl, IN PLACE (bucket region is block-exclusive) ----
__global__ __launch_bounds__(256) void sortB_kernel(int2* __restrict__ recs0, int2* __restrict__ recs1,
                                                    const int* __restrict__ cursor,
                                                    const int* __restrict__ counts, int NBK) {
  __shared__ int cnt_lds[64];
  __shared__ int cur_lds[64];
  int z = blockIdx.y;
  int b = blockIdx.x;
  int2* __restrict__ recs = z ? recs1 : recs0;
  int start = cursor[(size_t)z * NBK + b];
  int cnt = counts[(size_t)z * NBK + b];
  int t = threadIdx.x;

  for (int cbase = 0; cbase < cnt; cbase += 2048) {
    int ccnt = min(2048, cnt - cbase);
    int2 r[8];
    int dl[8];
    if (t < 64) cnt_lds[t] = 0;
    __syncthreads();
#pragma unroll
    for (int k = 0; k < 8; ++k) {
      int idx = k * 256 + t;
      if (idx < ccnt) {
        r[k] = recs[start + cbase + idx];
        dl[k] = ((unsigned)r[k].y) >> 26;
        atomicAdd(&cnt_lds[dl[k]], 1);
      }
    }
    __syncthreads();
    if (t < 64) {  // wave 0: exclusive prefix over 64 bins
      int c = cnt_lds[t];
      int x = c;
#pragma unroll
      for (int off = 1; off < 64; off <<= 1) {
        int y = __shfl_up(x, off);
        if (t >= off) x += y;
      }
      cur_lds[t] = x - c;
    }
    __syncthreads();
#pragma unroll
    for (int k = 0; k < 8; ++k) {
      int idx = k * 256 + t;
      if (idx < ccnt) {
        int pos = atomicAdd(&cur_lds[dl[k]], 1);
        recs[start + cbase + pos] = r[k];
      }
    }
    __syncthreads();
  }
}

struct EdgeArgs {
  const float* e[2];
  const int2* recs[2];
  const unsigned short* We[2];
  const float* bmsg[2];
  const unsigned short* Ps[2];
  const unsigned short* Pd[2];
  float* agg[2];
};

// ---- edge GEMM over dst-sorted tiles ----
// acc = e@We + Ps[src] (via identity-MFMA) + b (acc init);
// transposed swizzled x^T in LDS; flush: agg[dst] += relu(x + Pd[dst]) per segment.
__global__ __launch_bounds__(256) void edge_sorted_kernel(EdgeArgs ea, int E) {
  __shared__ unsigned short x_lds[4][64 * 64];  // 4 waves x 8KB, x^T[col][row]

  int z = blockIdx.y;
  const float* __restrict__ e = ea.e[z];
  const int2* __restrict__ recs = ea.recs[z];
  const unsigned short* __restrict__ Psrc = ea.Ps[z];
  const unsigned short* __restrict__ Pdst = ea.Pd[z];
  float* __restrict__ agg = ea.agg[z];

  int lane = threadIdx.x & 63;
  int wv = threadIdx.x >> 6;
  int base = (blockIdx.x * 4 + wv) * 64;
  if (base >= E) return;  // no barriers anywhere: per-wave exit is safe
  int l15 = lane & 15, lh = lane >> 4;
  unsigned short* xw = &x_lds[wv][0];

  // this wave's 64 sorted slots (one coalesced 8B load)
  int slot = base + lane;
  int el = 0, sl = 0, dl = 0;
  if (slot < E) {
    int2 rc = recs[slot];
    el = rc.x & 0x1FFFFF;
    sl = rc.y & 0x3FFFFFF;
    dl = (((rc.x >> 21) & 0x7FF) << 6) | (int)(((unsigned)rc.y) >> 26);
  }

  short8 bfr[2][4];
  load_bfrags(ea.We[z], bfr, lane);

  // identity B-fragments: I[k=lh*8+i][col=half*16+l15]
  short8 idf[2];
#pragma unroll
  for (int half = 0; half < 2; ++half) {
    short8 v;
#pragma unroll
    for (int i = 0; i < 8; ++i)
      v[i] = (short)((lh * 8 + i == half * 16 + l15) ? 0x3F80 : 0);
    idf[half] = v;
  }

  // bias folded into accumulator init (per-col broadcast)
  const float* bmsg = ea.bmsg[z];
  f32x4 acc[4][4];
#pragma unroll
  for (int ct = 0; ct < 4; ++ct) {
    float b = bmsg[ct * 16 + l15];
    f32x4 bb = (f32x4){b, b, b, b};
#pragma unroll
    for (int rt = 0; rt < 4; ++rt) acc[rt][ct] = bb;
  }

#pragma unroll
  for (int rt = 0; rt < 4; ++rt) {
    int sr = rt * 16 + l15;
    int er = __shfl(el, sr);
    int hr = __shfl(sl, sr);
    const fvec4* pr = reinterpret_cast<const fvec4*>(e + ((size_t)er << 6));
    const ushort8* ps = reinterpret_cast<const ushort8*>(Psrc + ((size_t)hr << 6));
    short8 aE0 = cvt8(pr[lh * 2], pr[lh * 2 + 1]);
    short8 aE1 = cvt8(pr[8 + lh * 2], pr[8 + lh * 2 + 1]);
    union { ushort8 u; short8 s; } aP0, aP1;
    aP0.u = ps[lh];
    aP1.u = ps[4 + lh];
#pragma unroll
    for (int ct = 0; ct < 4; ++ct) {
      acc[rt][ct] = __builtin_amdgcn_mfma_f32_16x16x32_bf16(aE0, bfr[0][ct], acc[rt][ct], 0, 0, 0);
      acc[rt][ct] = __builtin_amdgcn_mfma_f32_16x16x32_bf16(aE1, bfr[1][ct], acc[rt][ct], 0, 0, 0);
    }
    acc[rt][0] = __builtin_amdgcn_mfma_f32_16x16x32_bf16(aP0.s, idf[0], acc[rt][0], 0, 0, 0);
    acc[rt][1] = __builtin_amdgcn_mfma_f32_16x16x32_bf16(aP0.s, idf[1], acc[rt][1], 0, 0, 0);
    acc[rt][2] = __builtin_amdgcn_mfma_f32_16x16x32_bf16(aP1.s, idf[0], acc[rt][2], 0, 0, 0);
    acc[rt][3] = __builtin_amdgcn_mfma_f32_16x16x32_bf16(aP1.s, idf[1], acc[rt][3], 0, 0, 0);
  }

  // ---- epilogue: x^T[col][row] swizzled, 16 x ds_write_b64
#pragma unroll
  for (int rt = 0; rt < 4; ++rt)
#pragma unroll
    for (int ct = 0; ct < 4; ++ct) {
      int col = ct * 16 + l15;
      int byte = (col << 7) + ((rt * 32 + lh * 8) ^ ((col & 7) << 4));
      uint2 d;
      d.x = pk2(acc[rt][ct][0], acc[rt][ct][1]);
      d.y = pk2(acc[rt][ct][2], acc[rt][ct][3]);
      *reinterpret_cast<uint2*>(reinterpret_cast<char*>(xw) + byte) = d;
    }

  asm volatile("s_waitcnt lgkmcnt(0)" ::: "memory");
  __builtin_amdgcn_sched_barrier(0);

  // ---- flush: lane owns column `lane`; 8 x ds_read_b128 reads the whole column
  ushort8 xv[8];
#pragma unroll
  for (int i = 0; i < 8; ++i) {
    int byte = (lane << 7) + ((i * 16) ^ ((lane & 7) << 4));
    xv[i] = *reinterpret_cast<ushort8*>(reinterpret_cast<char*>(xw) + byte);
  }

  int dprev = __shfl_up(dl, 1);
  unsigned long long bnd = __ballot(lane > 0 && dl != dprev);
  int vrows = min(64, E - base);  // wave-uniform; rows >= vrows are padding

  float racc = 0.f, pdv = 0.f;
  int dcur = -1;
#pragma unroll
  for (int r = 0; r < 64; ++r) {
    bool newseg = (r == 0) || ((bnd >> r) & 1ull);
    if (newseg) {  // wave-uniform scalar branch
      if (dcur >= 0) atomicAdd(&agg[(size_t)dcur * 64 + lane], racc);
      dcur = __shfl(dl, r);
      racc = 0.f;
      pdv = bf2f(Pdst[(size_t)dcur * 64 + lane]);  // one 128B row per segment
    }
    float v = fmaxf(bf2f(xv[r >> 3][r & 7]) + pdv, 0.f);
    racc += (r < vrows) ? v : 0.f;  // padding contributes 0
  }
  if (dcur >= 0) atomicAdd(&agg[(size_t)dcur * 64 + lane], racc);
}

struct NodeArgs {
  const float* agg[2];
  const unsigned short* T[2];
  const float* bn[2];
  unsigned short* U[2];
};

// U = bf16(relu(T + agg@Wagg + b_node)); agg split hi+lo bf16 for accuracy
__global__ __launch_bounds__(256) void node_kernel(const unsigned short* __restrict__ Wf,
                                                   NodeArgs na, int N) {
  int z = blockIdx.y;
  const float* __restrict__ agg = na.agg[z];
  const unsigned short* __restrict__ T = na.T[z];
  const float* __restrict__ bn = na.bn[z];
  unsigned short* __restrict__ U = na.U[z];
  int lane = threadIdx.x & 63;
  int wv = threadIdx.x >> 6;
  int rowbase = blockIdx.x * 256 + wv * 64;
  int l15 = lane & 15, lh = lane >> 4;

  short8 bfr[2][4];
  load_bfrags(Wf + (size_t)(8 + z) * 4096, bfr, lane);

  f32x4 acc[4][4];
#pragma unroll
  for (int rt = 0; rt < 4; ++rt)
#pragma unroll
    for (int ct = 0; ct < 4; ++ct) acc[rt][ct] = (f32x4){0.f, 0.f, 0.f, 0.f};

#pragma unroll
  for (int rt = 0; rt < 4; ++rt) {
    int row = rowbase + rt * 16 + l15;
    int rc = row < N ? row : 0;
    const fvec4* p = reinterpret_cast<const fvec4*>(agg + (size_t)rc * 64);
#pragma unroll
    for (int ks = 0; ks < 2; ++ks) {
      fvec4 p0 = p[ks * 8 + lh * 2], p1 = p[ks * 8 + lh * 2 + 1];
      short8 ahi = cvt8(p0, p1);
      fvec4 q0, q1;
#pragma unroll
      for (int i = 0; i < 4; ++i) {
        q0[i] = p0[i] - bf2f((unsigned short)ahi[i]);
        q1[i] = p1[i] - bf2f((unsigned short)ahi[i + 4]);
      }
      short8 alo = cvt8(q0, q1);
#pragma unroll
      for (int ct = 0; ct < 4; ++ct) {
        acc[rt][ct] = __builtin_amdgcn_mfma_f32_16x16x32_bf16(ahi, bfr[ks][ct], acc[rt][ct], 0, 0, 0);
        acc[rt][ct] = __builtin_amdgcn_mfma_f32_16x16x32_bf16(alo, bfr[ks][ct], acc[rt][ct], 0, 0, 0);
      }
    }
  }

  float bv[4];
#pragma unroll
  for (int ct = 0; ct < 4; ++ct) bv[ct] = bn[ct * 16 + l15];

#pragma unroll
  for (int rt = 0; rt < 4; ++rt)
#pragma unroll
    for (int rg = 0; rg < 4; ++rg) {
      int row = rowbase + rt * 16 + lh * 4 + rg;
      if (row < N) {
#pragma unroll
        for (int ct = 0; ct < 4; ++ct) {
          int c = ct * 16 + l15;
          float v = acc[rt][ct][rg] + bf2f(T[(size_t)row * 64 + c]) + bv[ct];
          U[(size_t)row * 64 + c] = f2bf(fmaxf(v, 0.0f));
        }
      }
    }
}

// attention over the 2-way stack; 4 threads per node
__global__ __launch_bounds__(256) void attn_kernel(
    const unsigned short* __restrict__ U0, const unsigned short* __restrict__ U1,
    const float* __restrict__ l1w, const float* __restrict__ l1b, const float* __restrict__ l2w,
    float* __restrict__ out, int N) {
  int t = threadIdx.x;
  int node = blockIdx.x * 64 + (t >> 2);
  int q = t & 3;
  if (node >= N) return;
  size_t b0 = (size_t)node * 64;

  float a0[8], a1[8];
#pragma unroll
  for (int i = 0; i < 8; ++i) { a0[i] = l1b[q * 8 + i]; a1[i] = a0[i]; }

  for (int k = 0; k < 64; ++k) {
    float u0 = bf2f(U0[b0 + k]);
    float u1 = bf2f(U1[b0 + k]);
#pragma unroll
    for (int i = 0; i < 8; ++i) {
      float w = l1w[k * 32 + q * 8 + i];
      a0[i] += u0 * w;
      a1[i] += u1 * w;
    }
  }
  float w0 = 0.f, w1 = 0.f;
#pragma unroll
  for (int i = 0; i < 8; ++i) {
    float l2 = l2w[q * 8 + i];
    w0 += tanhf(a0[i]) * l2;
    w1 += tanhf(a1[i]) * l2;
  }
  w0 += __shfl_xor(w0, 1, 4); w0 += __shfl_xor(w0, 2, 4);
  w1 += __shfl_xor(w1, 1, 4); w1 += __shfl_xor(w1, 2, 4);

  float m = fmaxf(w0, w1);
  float e0 = expf(w0 - m), e1 = expf(w1 - m);
  float inv = 1.0f / (e0 + e1);
  float be0 = e0 * inv, be1 = e1 * inv;

#pragma unroll
  for (int j = 0; j < 16; ++j) {
    int c = q * 16 + j;
    out[b0 + c] = be0 * bf2f(U0[b0 + c]) + be1 * bf2f(U1[b0 + c]);
  }
}

static inline size_t au(size_t x) { return (x + 255) & ~(size_t)255; }

extern "C" void kernel_launch(void* const* d_in, const int* in_sizes, int n_in,
                              void* d_out, int out_size, void* d_ws, size_t ws_size,
                              hipStream_t stream) {
  const float* h      = (const float*)d_in[0];
  const float* e_od   = (const float*)d_in[1];
  const float* e_ad   = (const float*)d_in[2];
  const int* src_od   = (const int*)d_in[3];
  const int* dst_od   = (const int*)d_in[4];
  const int* src_ad   = (const int*)d_in[5];
  const int* dst_ad   = (const int*)d_in[6];
  const float* W_src  = (const float*)d_in[7];
  const float* W_dst  = (const float*)d_in[8];
  const float* W_edge = (const float*)d_in[9];
  const float* b_msg  = (const float*)d_in[10];
  const float* W_self = (const float*)d_in[11];
  const float* W_agg  = (const float*)d_in[12];
  const float* b_node = (const float*)d_in[13];
  const float* l1w    = (const float*)d_in[14];
  const float* l1b    = (const float*)d_in[15];
  const float* l2w    = (const float*)d_in[16];
  float* out = (float*)d_out;

  int N = in_sizes[0] / 64;
  int E = in_sizes[1] / 64;
  int NBK = (N + 63) >> 6;  // 64-node dst buckets

  char* ws = (char*)d_ws;
  size_t off = 0;
  int* counts = (int*)(ws + off);   off += au((size_t)2 * NBK * sizeof(int));
  float* agg0 = (float*)(ws + off); off += (size_t)N * 64 * sizeof(float);
  float* agg1 = (float*)(ws + off); off += (size_t)N * 64 * sizeof(float);
  size_t zero_bytes = off;          // counts + agg0 + agg1 contiguous
  int* cursor = (int*)(ws + off);   off += au((size_t)2 * NBK * sizeof(int));
  int* gcur   = (int*)(ws + off);   off += au((size_t)2 * NBK * sizeof(int));
  int2* recs0 = (int2*)(ws + off);  off += au((size_t)E * sizeof(int2));
  int2* recs1 = (int2*)(ws + off);  off += au((size_t)E * sizeof(int2));
  unsigned short* Wf = (unsigned short*)(ws + off); off += au((size_t)10 * 4096 * sizeof(unsigned short));
  size_t NP = au((size_t)N * 64 * sizeof(unsigned short));
  unsigned short* Psrc0 = (unsigned short*)(ws + off); off += NP;
  unsigned short* Pdst0 = (unsigned short*)(ws + off); off += NP;
  unsigned short* Psrc1 = (unsigned short*)(ws + off); off += NP;
  unsigned short* Pdst1 = (unsigned short*)(ws + off); off += NP;
  unsigned short* T0    = (unsigned short*)(ws + off); off += NP;
  unsigned short* T1    = (unsigned short*)(ws + off); off += NP;
  unsigned short* U0 = Psrc0;  // dead after edge pass of graph 0
  unsigned short* U1 = Psrc1;  // dead after edge pass of graph 1

  hipMemsetAsync(ws, 0, zero_bytes, stream);

  // one-time weight prep: fragment-layout bf16 (10 matrices, 1 wave each)
  PrepArgs pw;
  pw.W[0] = W_src;         pw.W[1] = W_dst;
  pw.W[2] = W_src + 4096;  pw.W[3] = W_dst + 4096;
  pw.W[4] = W_self;        pw.W[5] = W_self + 4096;
  pw.W[6] = W_edge;        pw.W[7] = W_edge + 4096;
  pw.W[8] = W_agg;         pw.W[9] = W_agg + 4096;
  prep_w_kernel<<<10, 64, 0, stream>>>(pw, Wf);

  int nb = (N + 255) / 256;
  ProjArgs pa;
  pa.out[0] = Psrc0;
  pa.out[1] = Pdst0;
  pa.out[2] = Psrc1;
  pa.out[3] = Pdst1;
  pa.out[4] = T0;
  pa.out[5] = T1;
  proj_all_kernel<<<nb, 256, 0, stream>>>(h, Wf, pa, N);

  int nch = (E + CH - 1) / CH;
  hist_kernel<<<dim3(nch, 2), 256, 0, stream>>>(dst_od, dst_ad, counts, E, NBK);
  scan_kernel<<<2, 1024, 0, stream>>>(counts, cursor, gcur, NBK);
  scatterA_kernel<<<dim3(nch, 2), 256, 0, stream>>>(src_od, dst_od, src_ad, dst_ad, gcur,
                                                    recs0, recs1, E, NBK);
  sortB_kernel<<<dim3(NBK, 2), 256, 0, stream>>>(recs0, recs1, cursor, counts, NBK);

  int tiles = (E + 63) / 64;
  int eb = (tiles + 3) / 4;
  EdgeArgs ea;
  ea.e[0] = e_od;  ea.recs[0] = recs0; ea.We[0] = Wf + 6 * 4096; ea.bmsg[0] = b_msg;
  ea.Ps[0] = Psrc0; ea.Pd[0] = Pdst0; ea.agg[0] = agg0;
  ea.e[1] = e_ad;  ea.recs[1] = recs1; ea.We[1] = Wf + 7 * 4096; ea.bmsg[1] = b_msg + 64;
  ea.Ps[1] = Psrc1; ea.Pd[1] = Pdst1; ea.agg[1] = agg1;
  edge_sorted_kernel<<<dim3(eb, 2), 256, 0, stream>>>(ea, E);

  NodeArgs na;
  na.agg[0] = agg0; na.T[0] = T0; na.bn[0] = b_node;      na.U[0] = U0;
  na.agg[1] = agg1; na.T[1] = T1; na.bn[1] = b_node + 64; na.U[1] = U1;
  node_kernel<<<dim3(nb, 2), 256, 0, stream>>>(Wf, na, N);

  attn_kernel<<<(N + 63) / 64, 256, 0, stream>>>(U0, U1, l1w, l1b, l2w, out, N);
}